// Round 2
// baseline (256.708 us; speedup 1.0000x reference)
//
#include <hip/hip_runtime.h>
#include <hip/hip_bf16.h>

using bf16 = __hip_bfloat16;
typedef __attribute__((ext_vector_type(8))) short short8;
typedef __attribute__((ext_vector_type(4))) float floatx4;

#define NB 4
#define NSEQ 4096
#define DIM 1024
#define INNER 512
#define TOK (NB * NSEQ)   // 16384

// -------------------------- memory plan (no d_ws) ---------------------------
// xbuf = x input (64 MiB, restorable):
//   [0,2)   wkvb bf16 [1024][1024]     (stage 4; xbuf lo dead after stage 2)
//   [2,6)   M2 bf16 [4096][512]        (stage 8)
//   [6,14)  W2 bf16 [4096][1024]       (stage 9)
//   [32,48) xb rows 0..8191            (stage 2: reads xbuf[0,32) - disjoint)
//   [48,64) xb rows 8192..16383        (stage 3 copy from d_out[0,16))
// d_out (64 MiB):
//   [0,16)  xb-hi staging              (stage 1; relocated by stage 3)
//   [0,32)  kv bf16 [16384][1024]      (stage 5 writes, stage 7 reads)
//   [0,64)  final output              (stage 10)
// wbuf = w_qkv input (6 MiB fp32):
//   [0,2)   wq fp32 (pristine, read by transpose)
//   [2,3)   wqT bf16 [1024][512]       (after stage 4 consumed w_kv fp32)
//   [3,3.5) ctx fp32 [32][64][64]

__device__ inline unsigned short f2bf(float x) {
  union { bf16 h; unsigned short u; } c; c.h = __float2bfloat16(x); return c.u;
}
__device__ inline float bf2f(unsigned short u) {
  return __uint_as_float((unsigned)u << 16);
}
__device__ inline void cvt8(const float* __restrict__ src, bf16* dst) {
  const float4 a = ((const float4*)src)[0];
  const float4 b = ((const float4*)src)[1];
  union { uint4 u; bf16 h[8]; } p;
  p.h[0] = __float2bfloat16(a.x); p.h[1] = __float2bfloat16(a.y);
  p.h[2] = __float2bfloat16(a.z); p.h[3] = __float2bfloat16(a.w);
  p.h[4] = __float2bfloat16(b.x); p.h[5] = __float2bfloat16(b.y);
  p.h[6] = __float2bfloat16(b.z); p.h[7] = __float2bfloat16(b.w);
  *(uint4*)dst = p.u;
}

// async global->LDS, 16 B per lane; HW writes lane i at ldsbase + i*16.
__device__ inline void gload_lds16(const bf16* g, bf16* ldsbase) {
  __builtin_amdgcn_global_load_lds(
      (const __attribute__((address_space(1))) void*)g,
      (__attribute__((address_space(3))) void*)ldsbase, 16, 0, 0);
}

#define WAITVM(N) asm volatile("s_waitcnt vmcnt(" #N ")" ::: "memory")

// ---------------------------------------------------------------------------
__global__ __launch_bounds__(256)
void convert_x(const float* __restrict__ x, bf16* __restrict__ xb) {
  const size_t i = (size_t)blockIdx.x * 256 + threadIdx.x;
  cvt8(x + i * 8, xb + i * 8);
}

__global__ __launch_bounds__(256)
void copy16(const uint4* __restrict__ src, uint4* __restrict__ dst) {
  const size_t i = (size_t)blockIdx.x * 256 + threadIdx.x;
  dst[i] = src[i];
}

__global__ void zero_ctx(float* __restrict__ ctx) {
  ((float4*)ctx)[blockIdx.x * 256 + threadIdx.x] = make_float4(0.f, 0.f, 0.f, 0.f);
}

// ---------------------------------------------------------------------------
// Legacy 128x128 GEMM (kept for stage 9, where M=4096 gives better CU
// coverage at 128 tiles). C = A[M,K] @ W[N,K]^T (+bias).
// ---------------------------------------------------------------------------
template <typename TO, bool BIAS>
__global__ __launch_bounds__(256, 4)
void gemm_bt(const bf16* __restrict__ A, int lda,
             const bf16* __restrict__ W, size_t wbatch, int mTiles,
             const float* __restrict__ bias,
             TO* __restrict__ C, int ldc, int K) {
  __shared__ __align__(16) bf16 As[128 * 64];
  __shared__ __align__(16) bf16 Bs[128 * 64];

  const int tid    = threadIdx.x;
  const int p      = blockIdx.x;
  const int m_tile = p % mTiles;
  const int n_tile = p / mTiles;
  const int m0     = m_tile * 128;
  const int n0     = n_tile * 128;
  if (wbatch) W += (size_t)(m_tile >> 5) * wbatch;

  const int wave = tid >> 6;
  const int lane = tid & 63;
  const int wr   = (wave >> 1) * 64;
  const int wc   = (wave & 1) * 64;
  const int quad = lane >> 4;
  const int r16  = lane & 15;
  const int rxor = r16 & 7;
  const int lrow = lane >> 3;
  const int lcol = lane & 7;
  const int gchunk = lcol ^ lrow;

  floatx4 acc[4][4];
#pragma unroll
  for (int i = 0; i < 4; ++i)
#pragma unroll
    for (int j = 0; j < 4; ++j) acc[i][j] = (floatx4)0.0f;

  const int ksteps = K >> 6;
  for (int kt = 0; kt < ksteps; ++kt) {
    const int k0 = kt << 6;
#pragma unroll
    for (int t = 0; t < 4; ++t) {
      const int s   = wave * 4 + t;
      const int row = s * 8 + lrow;
      gload_lds16(A + (size_t)(m0 + row) * lda + k0 + gchunk * 8, As + s * 512);
      gload_lds16(W + (size_t)(n0 + row) * K   + k0 + gchunk * 8, Bs + s * 512);
    }
    __syncthreads();
#pragma unroll
    for (int kk = 0; kk < 64; kk += 32) {
      const int cbase = kk >> 3;
      short8 af[4], bfg[4];
#pragma unroll
      for (int i = 0; i < 4; ++i)
        af[i] = *(const short8*)(As + (wr + i * 16 + r16) * 64 + (((quad + cbase) ^ rxor) << 3));
#pragma unroll
      for (int j = 0; j < 4; ++j)
        bfg[j] = *(const short8*)(Bs + (wc + j * 16 + r16) * 64 + (((quad + cbase) ^ rxor) << 3));
#pragma unroll
      for (int i = 0; i < 4; ++i)
#pragma unroll
        for (int j = 0; j < 4; ++j)
          acc[i][j] = __builtin_amdgcn_mfma_f32_16x16x32_bf16(af[i], bfg[j], acc[i][j], 0, 0, 0);
    }
    __syncthreads();
  }

#pragma unroll
  for (int j = 0; j < 4; ++j) {
    const int col = n0 + wc + j * 16 + r16;
    const float bv = BIAS ? bias[col] : 0.0f;
#pragma unroll
    for (int i = 0; i < 4; ++i) {
      const int rowb = m0 + wr + i * 16 + quad * 4;
#pragma unroll
      for (int r = 0; r < 4; ++r) {
        const float v = acc[i][j][r] + bv;
        if constexpr (sizeof(TO) == 2)
          C[(size_t)(rowb + r) * ldc + col] = __float2bfloat16(v);
        else
          C[(size_t)(rowb + r) * ldc + col] = v;
      }
    }
  }
}

// ---------------------------------------------------------------------------
// 256x256 4-phase counted-vmcnt GEMM: C = A[M,K] @ W[N,K]^T (+bias).
// 512 threads = 8 waves (2M x 4N), per-wave 128x64 output, BK=64,
// STATIC double-buffered 128 KiB LDS. Quadrants per K-tile:
// P1 (0,0), P2 (0,1), P3 (1,1), P4 (1,0). Region-free analysis (this wave
// decomposition): A[db] fully consumed after P3's MFMA; B[db] only after
// P4's ds_reads; buffer db^1 is free all iteration (its reads ended at the
// previous iteration's closing barrier). Stage schedule:
//   P1: stage B(T+1) -> Bs[db^1]   (free buffer)
//   P4: stage A(T+2) -> As[db]     (A[db] consumed at P3, barrier passed)
// Per wave 8 loads/iter; at P4-end WAITVM(4) retires A(T+1)+B(T+1) exactly
// (tile T+1 landed before the closing barrier), leaving A(T+2) in flight —
// counted vmcnt, never 0 mid-loop. Tail (T>=nk-2): WAITVM(0).
// XOR swizzle identical to gemm_bt (verified, 0 bank conflicts).
// ---------------------------------------------------------------------------
template <typename TO, bool BIAS>
__global__ __launch_bounds__(512, 2)
void gemm256(const bf16* __restrict__ A, int lda,
             const bf16* __restrict__ W, size_t wbatch, int mTiles,
             const float* __restrict__ bias,
             TO* __restrict__ C, int ldc, int K) {
  __shared__ __align__(16) bf16 As[2 * 16384];   // [2][256][64]
  __shared__ __align__(16) bf16 Bs[2 * 16384];   // [2][256][64]

  const int tid    = threadIdx.x;
  const int p      = blockIdx.x;
  const int m_tile = p % mTiles;
  const int n_tile = p / mTiles;
  const int m0     = m_tile * 256;
  const int n0     = n_tile * 256;
  if (wbatch) W += (size_t)(m_tile >> 4) * wbatch;   // 4096-row batches / 256

  const int wave = tid >> 6;
  const int lane = tid & 63;
  const int wm   = wave >> 2;       // 0..1
  const int wn   = wave & 3;        // 0..3
  const int quad = lane >> 4;
  const int r16  = lane & 15;
  const int rxor = r16 & 7;
  const int lrow = lane >> 3;
  const int lcol = lane & 7;
  const int gchunk = lcol ^ lrow;

  const int nk = K >> 6;

  // Stage one full 256x64 tile of A (or B) for K-tile T: 4 loads/wave.
  auto stageA = [&](int T) {
    bf16* lp = As + (T & 1) * 16384;
#pragma unroll
    for (int c = 0; c < 4; ++c) {
      const int rb = c * 64 + wave * 8;   // wave-uniform base row
      gload_lds16(A + (size_t)(m0 + rb + lrow) * lda + T * 64 + gchunk * 8,
                  lp + rb * 64);
    }
  };
  auto stageB = [&](int T) {
    bf16* lp = Bs + (T & 1) * 16384;
#pragma unroll
    for (int c = 0; c < 4; ++c) {
      const int rb = c * 64 + wave * 8;
      gload_lds16(W + (size_t)(n0 + rb + lrow) * K + T * 64 + gchunk * 8,
                  lp + rb * 64);
    }
  };

  floatx4 acc[8][4];
#pragma unroll
  for (int i = 0; i < 8; ++i)
#pragma unroll
    for (int j = 0; j < 4; ++j) acc[i][j] = (floatx4)0.0f;

  short8 a[4][2], b[2][2];

#define LDA_FRAGS(mh) do {                                                    \
  _Pragma("unroll")                                                           \
  for (int i = 0; i < 4; ++i) {                                               \
    const bf16* base = As + db * 16384 +                                      \
        (wm * 128 + (mh) * 64 + i * 16 + r16) * 64;                           \
    a[i][0] = *(const short8*)(base + ((quad ^ rxor) << 3));                  \
    a[i][1] = *(const short8*)(base + (((4 + quad) ^ rxor) << 3));            \
  } } while (0)

#define LDB_FRAGS(nh) do {                                                    \
  _Pragma("unroll")                                                           \
  for (int j = 0; j < 2; ++j) {                                               \
    const bf16* base = Bs + db * 16384 +                                      \
        (wn * 64 + (nh) * 32 + j * 16 + r16) * 64;                            \
    b[j][0] = *(const short8*)(base + ((quad ^ rxor) << 3));                  \
    b[j][1] = *(const short8*)(base + (((4 + quad) ^ rxor) << 3));            \
  } } while (0)

#define MFMA_QUAD(mh, nh) do {                                                \
  _Pragma("unroll")                                                           \
  for (int i = 0; i < 4; ++i)                                                 \
  _Pragma("unroll")                                                           \
  for (int j = 0; j < 2; ++j) {                                               \
    acc[(mh)*4+i][(nh)*2+j] = __builtin_amdgcn_mfma_f32_16x16x32_bf16(        \
        a[i][0], b[j][0], acc[(mh)*4+i][(nh)*2+j], 0, 0, 0);                  \
    acc[(mh)*4+i][(nh)*2+j] = __builtin_amdgcn_mfma_f32_16x16x32_bf16(        \
        a[i][1], b[j][1], acc[(mh)*4+i][(nh)*2+j], 0, 0, 0);                  \
  } } while (0)

  // Prologue: tile 0 (A+B), then A of tile 1. 12 loads; retire tile 0.
  stageA(0); stageB(0);
  if (nk > 1) { stageA(1); WAITVM(4); }
  else        { WAITVM(0); }
  __builtin_amdgcn_s_barrier();

  for (int T = 0; T < nk; ++T) {
    const int db = T & 1;
    // ---- P1: quadrant (0,0); stage B(T+1) into the free buffer db^1
    LDA_FRAGS(0); LDB_FRAGS(0);
    if (T + 1 < nk) stageB(T + 1);
    __builtin_amdgcn_s_barrier();
    __builtin_amdgcn_s_setprio(1);
    MFMA_QUAD(0, 0);
    __builtin_amdgcn_s_setprio(0);
    __builtin_amdgcn_s_barrier();
    // ---- P2: quadrant (0,1)
    LDB_FRAGS(1);
    __builtin_amdgcn_s_barrier();
    __builtin_amdgcn_s_setprio(1);
    MFMA_QUAD(0, 1);
    __builtin_amdgcn_s_setprio(0);
    __builtin_amdgcn_s_barrier();
    // ---- P3: quadrant (1,1) — last A[db] reads, consumed by this MFMA
    LDA_FRAGS(1);
    __builtin_amdgcn_s_barrier();
    __builtin_amdgcn_s_setprio(1);
    MFMA_QUAD(1, 1);
    __builtin_amdgcn_s_setprio(0);
    __builtin_amdgcn_s_barrier();
    // ---- P4: quadrant (1,0); A[db] now dead -> stage A(T+2) into it
    LDB_FRAGS(0);
    if (T + 2 < nk) stageA(T + 2);
    __builtin_amdgcn_s_barrier();
    __builtin_amdgcn_s_setprio(1);
    MFMA_QUAD(1, 0);
    __builtin_amdgcn_s_setprio(0);
    if (T < nk - 2) WAITVM(4);   // retire A(T+1)+B(T+1); A(T+2) stays in flight
    else            WAITVM(0);   // tail drain
    __builtin_amdgcn_s_barrier();
  }

#undef LDA_FRAGS
#undef LDB_FRAGS
#undef MFMA_QUAD

  // D mapping (verified m89/m91): row = quad*4 + reg, col = lane&15
#pragma unroll
  for (int jj = 0; jj < 4; ++jj) {
    const int col = n0 + wn * 64 + jj * 16 + r16;
    const float bv = BIAS ? bias[col] : 0.0f;
#pragma unroll
    for (int ii = 0; ii < 8; ++ii) {
      const int rowb = m0 + wm * 128 + ii * 16 + quad * 4;
#pragma unroll
      for (int r = 0; r < 4; ++r) {
        const float v = acc[ii][jj][r] + bv;
        if constexpr (sizeof(TO) == 2)
          C[(size_t)(rowb + r) * ldc + col] = __float2bfloat16(v);
        else
          C[(size_t)(rowb + r) * ldc + col] = v;
      }
    }
  }
}

// ---------------------------------------------------------------------------
// softmax(k over dh=64) + ctx[bh][d][e] += sum_n sk[n,d]*v[n,e]  via MFMA.
// ---------------------------------------------------------------------------
__global__ __launch_bounds__(256)
void softmax_context(const unsigned short* __restrict__ kv, float* __restrict__ ctx) {
  __shared__ unsigned short skT[64 * 130];
  __shared__ unsigned short vT [64 * 130];

  const int tid   = threadIdx.x;
  const int wave  = tid >> 6;
  const int lane  = tid & 63;
  const int bh    = blockIdx.x >> 4;
  const int slice = blockIdx.x & 15;
  const int b     = bh >> 3, h = bh & 7;

  const int quad = lane >> 4;
  const int r16  = lane & 15;
  const int d0   = wave * 16;

  floatx4 acc[4];
#pragma unroll
  for (int j = 0; j < 4; ++j) acc[j] = (floatx4)0.0f;

  const int rgrp = tid >> 3;
  const int c    = tid & 7;

  for (int ch = 0; ch < 2; ++ch) {
#pragma unroll
    for (int p = 0; p < 4; ++p) {
      const int r = p * 32 + rgrp;
      const size_t rowbase =
          (size_t)(b * NSEQ + slice * 256 + ch * 128 + r) * 1024 + h * 64;
      const uint4 k8 = *(const uint4*)(kv + rowbase + c * 8);
      const uint4 v8 = *(const uint4*)(kv + rowbase + 512 + c * 8);
      const unsigned short* kb = (const unsigned short*)&k8;
      const unsigned short* vb = (const unsigned short*)&v8;

      float kf[8];
#pragma unroll
      for (int j = 0; j < 8; ++j) kf[j] = bf2f(kb[j]);
      float mx = kf[0];
#pragma unroll
      for (int j = 1; j < 8; ++j) mx = fmaxf(mx, kf[j]);
      mx = fmaxf(mx, __shfl_xor(mx, 1, 64));
      mx = fmaxf(mx, __shfl_xor(mx, 2, 64));
      mx = fmaxf(mx, __shfl_xor(mx, 4, 64));
      float e[8]; float s = 0.0f;
#pragma unroll
      for (int j = 0; j < 8; ++j) { e[j] = __expf(kf[j] - mx); s += e[j]; }
      s += __shfl_xor(s, 1, 64);
      s += __shfl_xor(s, 2, 64);
      s += __shfl_xor(s, 4, 64);
      const float inv = 1.0f / s;
#pragma unroll
      for (int j = 0; j < 8; ++j) {
        const int d = c * 8 + j;
        skT[d * 130 + r] = f2bf(e[j] * inv);
        vT [d * 130 + r] = vb[j];
      }
    }
    __syncthreads();

#pragma unroll
    for (int kk = 0; kk < 4; ++kk) {
      const int kof = kk * 32 + quad * 8;
      union { short8 v; unsigned u[4]; } afr;
      {
        const unsigned* q = (const unsigned*)(skT + (d0 + r16) * 130 + kof);
        afr.u[0] = q[0]; afr.u[1] = q[1]; afr.u[2] = q[2]; afr.u[3] = q[3];
      }
#pragma unroll
      for (int j = 0; j < 4; ++j) {
        union { short8 v; unsigned u[4]; } bfr;
        const unsigned* q = (const unsigned*)(vT + (j * 16 + r16) * 130 + kof);
        bfr.u[0] = q[0]; bfr.u[1] = q[1]; bfr.u[2] = q[2]; bfr.u[3] = q[3];
        acc[j] = __builtin_amdgcn_mfma_f32_16x16x32_bf16(afr.v, bfr.v, acc[j], 0, 0, 0);
      }
    }
    __syncthreads();
  }

  float* cg = ctx + (size_t)bh * 4096;
#pragma unroll
  for (int j = 0; j < 4; ++j) {
    const int e = j * 16 + r16;
#pragma unroll
    for (int r = 0; r < 4; ++r) {
      const int d = d0 + quad * 4 + r;
      atomicAdd(cg + d * 64 + e, acc[j][r]);
    }
  }
}

// ---------------------------------------------------------------------------
// wqT[c][c'] = bf16(wq[c'][c])   wq fp32 [512][1024]
// ---------------------------------------------------------------------------
__global__ __launch_bounds__(256)
void transpose_wq(const float* __restrict__ wq, bf16* __restrict__ wqT) {
  __shared__ unsigned short t[64 * 68];
  const int tid = threadIdx.x;
  const int c0  = blockIdx.x * 64;
  const int r0  = blockIdx.y * 64;

#pragma unroll
  for (int l = 0; l < 4; ++l) {
    const int s = l * 256 + tid;
    const int row = s >> 4, col4 = s & 15;
    const float4 v = *(const float4*)(wq + (size_t)(r0 + row) * 1024 + c0 + col4 * 4);
    t[row * 68 + col4 * 4 + 0] = f2bf(v.x);
    t[row * 68 + col4 * 4 + 1] = f2bf(v.y);
    t[row * 68 + col4 * 4 + 2] = f2bf(v.z);
    t[row * 68 + col4 * 4 + 3] = f2bf(v.w);
  }
  __syncthreads();
#pragma unroll
  for (int l = 0; l < 2; ++l) {
    const int s = l * 256 + tid;
    const int cc = s >> 3, g = s & 7;
    union { uint4 u; unsigned short h[8]; } o;
#pragma unroll
    for (int u = 0; u < 8; ++u) o.h[u] = t[(g * 8 + u) * 68 + cc];
    *(uint4*)((unsigned short*)wqT + (size_t)(c0 + cc) * 512 + r0 + g * 8) = o.u;
  }
}

// ---------------------------------------------------------------------------
// M2[b*1024+o][h*64+d] = sum_e w_out[o][h*64+e] * ctx[b,h][d][e]; w_out fp32.
// ---------------------------------------------------------------------------
__global__ __launch_bounds__(256)
void build_m2(const float* __restrict__ w_out, const float* __restrict__ ctx,
              bf16* __restrict__ M2) {
  __shared__ unsigned short wo_s[128 * 68];
  __shared__ __align__(16) float ctx_s[4096];

  const int tid = threadIdx.x;
  const int bh  = blockIdx.y;
  const int b   = bh >> 3, h = bh & 7;
  const int o0  = blockIdx.x * 128;

#pragma unroll
  for (int l = 0; l < 8; ++l) {
    const int s = l * 256 + tid;
    const int row = s >> 4, col4 = s & 15;
    const float4 v = *(const float4*)(w_out + (size_t)(o0 + row) * 512 + h * 64 + col4 * 4);
    wo_s[row * 68 + col4 * 4 + 0] = f2bf(v.x);
    wo_s[row * 68 + col4 * 4 + 1] = f2bf(v.y);
    wo_s[row * 68 + col4 * 4 + 2] = f2bf(v.z);
    wo_s[row * 68 + col4 * 4 + 3] = f2bf(v.w);
  }
  const float4* cg = (const float4*)(ctx + (size_t)bh * 4096);
#pragma unroll
  for (int l = 0; l < 4; ++l) ((float4*)ctx_s)[l * 256 + tid] = cg[l * 256 + tid];
  __syncthreads();

  const int o_loc = tid & 127;
  const int dbase = (tid >> 7) * 32;
  float acc[32];
#pragma unroll
  for (int d = 0; d < 32; ++d) acc[d] = 0.0f;

  for (int e = 0; e < 64; ++e) {
    const float wf = bf2f(wo_s[o_loc * 68 + e]);
#pragma unroll
    for (int d = 0; d < 32; ++d)
      acc[d] += wf * ctx_s[(dbase + d) * 64 + e];
  }

  union { uint4 u[4]; unsigned short h[32]; } o;
#pragma unroll
  for (int d = 0; d < 32; ++d) o.h[d] = f2bf(acc[d]);
  unsigned short* dst = (unsigned short*)M2 + (size_t)(b * 1024 + o0 + o_loc) * 512 + h * 64 + dbase;
#pragma unroll
  for (int i = 0; i < 4; ++i) ((uint4*)dst)[i] = o.u[i];
}

// ---------------------------------------------------------------------------
extern "C" void kernel_launch(void* const* d_in, const int* in_sizes, int n_in,
                              void* d_out, int out_size, void* d_ws, size_t ws_size,
                              hipStream_t stream) {
  const float* x     = (const float*)d_in[0];
  const float* w_qkv = (const float*)d_in[1];
  const float* w_out = (const float*)d_in[2];
  const float* b_out = (const float*)d_in[3];
  float* out = (float*)d_out;

  char* xbuf = (char*)d_in[0];
  char* wbuf = (char*)d_in[1];

  bf16*  wkvb = (bf16*)xbuf;                         // [0,2)
  bf16*  M2   = (bf16*)(xbuf + (size_t)2097152);     // [2,6)
  bf16*  W2   = (bf16*)(xbuf + (size_t)6291456);     // [6,14)
  bf16*  xb   = (bf16*)(xbuf + (size_t)33554432);    // [32,64): full xb
  bf16*  xbhi_stage = (bf16*)d_out;                  // d_out[0,16) temp
  bf16*  kv   = (bf16*)d_out;                        // d_out[0,32)
  bf16*  wqT  = (bf16*)(wbuf + 2097152);             // [2,3)
  float* ctx  = (float*)(wbuf + 3145728);            // [3,3.5)

  // 1) xb-hi = bf16(x rows 8192..16383) -> d_out[0,16)   (reads xbuf[32,64))
  convert_x<<<4096, 256, 0, stream>>>(x + (size_t)8192 * DIM, xbhi_stage);
  // 2) xb-lo = bf16(x rows 0..8191) -> xbuf[32,48)       (reads xbuf[0,32) - disjoint)
  convert_x<<<4096, 256, 0, stream>>>(x, xb);
  // 3) relocate xb-hi -> xbuf[48,64)  (x rows 12288+ dead after 1)
  copy16<<<4096, 256, 0, stream>>>((const uint4*)xbhi_stage,
                                   (uint4*)(xb + (size_t)8192 * DIM));
  // 4) wkvb = bf16(w_qkv rows 512..1535) -> xbuf[0,2)  (xbuf lo dead after 2)
  convert_x<<<512, 256, 0, stream>>>(w_qkv + (size_t)INNER * DIM, wkvb);

  // 5) kv = xb @ wkvb^T -> d_out[0,32). 256x256 tiles: 64 mTiles x 4 nTiles.
  gemm256<bf16, false><<<256, 512, 0, stream>>>(
      xb, DIM, wkvb, 0, 64, nullptr, kv, 1024, DIM);

  // 6) ctx zero + wqT transpose (w_kv fp32 region of wbuf dead after 4)
  zero_ctx<<<128, 256, 0, stream>>>(ctx);
  transpose_wq<<<dim3(16, 8), 256, 0, stream>>>(w_qkv, wqT);

  // 7) ctx = softmax(k)^T v
  softmax_context<<<512, 256, 0, stream>>>((const unsigned short*)kv, ctx);

  // 8) M2 = w_out folded through ctx -> xbuf[2,6)
  build_m2<<<dim3(8, 32), 256, 0, stream>>>(w_out, ctx, M2);

  // 9) W2 = M2 @ wqT^T -> xbuf[6,14). legacy 128-tile: grid 256, mTiles=32.
  gemm_bt<bf16, false><<<256, 256, 0, stream>>>(
      M2, 512, wqT, 0, 32, nullptr, W2, 1024, 512);

  // 10) out = xb @ W2[b]^T + b_out -> all of d_out (kv dead). 64x4 tiles.
  gemm256<float, true><<<256, 512, 0, stream>>>(
      xb, DIM, W2, (size_t)1048576, 64, b_out, out, DIM, DIM);
}

// Round 3
// 248.156 us; speedup vs baseline: 1.0345x; 1.0345x over previous
//
#include <hip/hip_runtime.h>
#include <hip/hip_bf16.h>

using bf16 = __hip_bfloat16;
typedef __attribute__((ext_vector_type(8))) short short8;
typedef __attribute__((ext_vector_type(4))) float floatx4;

#define NB 4
#define NSEQ 4096
#define DIM 1024
#define INNER 512
#define TOK (NB * NSEQ)   // 16384

// -------------------------- memory plan (no d_ws) ---------------------------
// xbuf = x input (64 MiB): PRISTINE fp32 the whole run (both big GEMMs read it
//   directly; the old convert/copy stages 1-3 are gone).
// d_out (64 MiB):
//   [0,32)   kv bf16 [16384][1024]   (stage 4 writes, stage 5 reads)
//   [32,34)  wkvb bf16 [1024][1024]  (stage 1; dead after stage 4)
//   [34,38)  M2 bf16 [4096][512]     (stage 6; dead after stage 7)
//   [38,39)  wqT bf16 [1024][512]    (stage 2; dead after stage 7)
//   [0,64)   final output            (stage 8 — reads NOTHING in d_out)
// wbuf = w_qkv input (6 MiB fp32):
//   [0,2)  wq fp32 (read by transpose, then dead)
//   [2,6)  w_kv fp32 (read by convert_wkv, then dead)
//   [3,3.5) ctx fp32 [32][64][64]    (stages 3/5/6; dead after 6)
//   [0,6)  W2 batches 0..2 bf16      (stage 7 writes, stage 8 reads)
// w_out buf (2 MiB fp32, d_in[2]): pristine through stage 6, then
//   W2 batch 3 bf16 [1024][1024]     (stage 7 writes, stage 8 reads)

__device__ inline unsigned short f2bf(float x) {
  union { bf16 h; unsigned short u; } c; c.h = __float2bfloat16(x); return c.u;
}
__device__ inline float bf2f(unsigned short u) {
  return __uint_as_float((unsigned)u << 16);
}
__device__ inline void cvt8(const float* __restrict__ src, bf16* dst) {
  const float4 a = ((const float4*)src)[0];
  const float4 b = ((const float4*)src)[1];
  union { uint4 u; bf16 h[8]; } p;
  p.h[0] = __float2bfloat16(a.x); p.h[1] = __float2bfloat16(a.y);
  p.h[2] = __float2bfloat16(a.z); p.h[3] = __float2bfloat16(a.w);
  p.h[4] = __float2bfloat16(b.x); p.h[5] = __float2bfloat16(b.y);
  p.h[6] = __float2bfloat16(b.z); p.h[7] = __float2bfloat16(b.w);
  *(uint4*)dst = p.u;
}

// async global->LDS, 16 B per lane; HW writes lane i at ldsbase + i*16.
__device__ inline void gload_lds16(const bf16* g, bf16* ldsbase) {
  __builtin_amdgcn_global_load_lds(
      (const __attribute__((address_space(1))) void*)g,
      (__attribute__((address_space(3))) void*)ldsbase, 16, 0, 0);
}

#define WAITVM(N) asm volatile("s_waitcnt vmcnt(" #N ")" ::: "memory")

// ---------------------------------------------------------------------------
__global__ __launch_bounds__(256)
void convert_x(const float* __restrict__ x, bf16* __restrict__ xb) {
  const size_t i = (size_t)blockIdx.x * 256 + threadIdx.x;
  cvt8(x + i * 8, xb + i * 8);
}

__global__ void zero_ctx(float* __restrict__ ctx) {
  ((float4*)ctx)[blockIdx.x * 256 + threadIdx.x] = make_float4(0.f, 0.f, 0.f, 0.f);
}

// ---------------------------------------------------------------------------
// 128x128 GEMM (stage 7). C = A[M,K] @ W[N,K]^T. Rows >= msplit go to Calt
// (W2 batch-3 home in the dead w_out buffer).
// ---------------------------------------------------------------------------
template <typename TO>
__global__ __launch_bounds__(256, 4)
void gemm_bt(const bf16* __restrict__ A, int lda,
             const bf16* __restrict__ W, int mTiles,
             TO* __restrict__ C, int ldc, int K,
             TO* __restrict__ Calt, int msplit) {
  __shared__ __align__(16) bf16 As[128 * 64];
  __shared__ __align__(16) bf16 Bs[128 * 64];

  const int tid    = threadIdx.x;
  const int p      = blockIdx.x;
  const int m_tile = p % mTiles;
  const int n_tile = p / mTiles;
  const int m0     = m_tile * 128;
  const int n0     = n_tile * 128;

  const int wave = tid >> 6;
  const int lane = tid & 63;
  const int wr   = (wave >> 1) * 64;
  const int wc   = (wave & 1) * 64;
  const int quad = lane >> 4;
  const int r16  = lane & 15;
  const int rxor = r16 & 7;
  const int lrow = lane >> 3;
  const int lcol = lane & 7;
  const int gchunk = lcol ^ lrow;

  floatx4 acc[4][4];
#pragma unroll
  for (int i = 0; i < 4; ++i)
#pragma unroll
    for (int j = 0; j < 4; ++j) acc[i][j] = (floatx4)0.0f;

  const int ksteps = K >> 6;
  for (int kt = 0; kt < ksteps; ++kt) {
    const int k0 = kt << 6;
#pragma unroll
    for (int t = 0; t < 4; ++t) {
      const int s   = wave * 4 + t;
      const int row = s * 8 + lrow;
      gload_lds16(A + (size_t)(m0 + row) * lda + k0 + gchunk * 8, As + s * 512);
      gload_lds16(W + (size_t)(n0 + row) * K   + k0 + gchunk * 8, Bs + s * 512);
    }
    __syncthreads();
#pragma unroll
    for (int kk = 0; kk < 64; kk += 32) {
      const int cbase = kk >> 3;
      short8 af[4], bfg[4];
#pragma unroll
      for (int i = 0; i < 4; ++i)
        af[i] = *(const short8*)(As + (wr + i * 16 + r16) * 64 + (((quad + cbase) ^ rxor) << 3));
#pragma unroll
      for (int j = 0; j < 4; ++j)
        bfg[j] = *(const short8*)(Bs + (wc + j * 16 + r16) * 64 + (((quad + cbase) ^ rxor) << 3));
#pragma unroll
      for (int i = 0; i < 4; ++i)
#pragma unroll
        for (int j = 0; j < 4; ++j)
          acc[i][j] = __builtin_amdgcn_mfma_f32_16x16x32_bf16(af[i], bfg[j], acc[i][j], 0, 0, 0);
    }
    __syncthreads();
  }

  TO* Cb = C; int radj = 0;
  if (Calt && m0 >= msplit) { Cb = Calt; radj = msplit; }
#pragma unroll
  for (int j = 0; j < 4; ++j) {
    const int col = n0 + wc + j * 16 + r16;
#pragma unroll
    for (int i = 0; i < 4; ++i) {
      const int rowb = m0 + wr + i * 16 + quad * 4 - radj;
#pragma unroll
      for (int r = 0; r < 4; ++r)
        Cb[(size_t)(rowb + r) * ldc + col] = __float2bfloat16(acc[i][j][r]);
    }
  }
}

// ---------------------------------------------------------------------------
// 256x256 4-phase counted-vmcnt GEMM, fp32 A: C = bf16(A)[M,K] @ W[N,K]^T.
// A is fp32 in HBM; reg-staged (8x global_load_dwordx4/wave/tile), converted
// to bf16 and ds_written with the XOR swizzle. B is bf16 via global_load_lds.
// 512 thr = 8 waves (2Mx4N), BK=64, double-buffered 128 KiB LDS.
// Phases P1(0,0) P2(0,1) P3(1,1) P4(1,0). Region-free analysis: As[db] fully
// consumed after P3's MFMA; Bs[db] after P4's ds_reads; buffer db^1 free all
// iteration. Issue order per tile T: P1 stageB(T+1)->Bs[db^1] [4 vm];
// P3 loadA(T+2)->regs [8 vm]. Waits: P2 WAITVM(4) retires exactly A(T+1)
// (oldest 8 of {A(T+1)8,B(T+1)4}), then cvt+ds_write -> As[db^1]; P4
// WAITVM(8) retires exactly B(T+1), leaving A(T+2) in flight (counted vmcnt,
// never 0 mid-loop). Tail: P4 WAITVM(0) when T+2>=nk. rA regs: consumed P2,
// re-issued P3 — disjoint live ranges, one 32-VGPR set.
// XCD swizzle (grid 256 = 8x32): xcd p&7 gets m_tiles [xcd*8, xcd*8+8) x all
// 4 n_tiles -> A-panel and B-panel L2 reuse within an XCD.
// ---------------------------------------------------------------------------
template <typename TO, bool BIAS>
__global__ __launch_bounds__(512, 2)
void gemm256f(const float* __restrict__ A,
              const bf16* __restrict__ W, size_t wbatch,
              const bf16* __restrict__ Walt,
              const float* __restrict__ bias,
              TO* __restrict__ C, int ldc, int K) {
  __shared__ __align__(16) bf16 As[2 * 16384];   // [2][256][64]
  __shared__ __align__(16) bf16 Bs[2 * 16384];

  const int tid  = threadIdx.x;
  const int p    = blockIdx.x;
  const int xcd  = p & 7, q = p >> 3;
  const int m_tile = xcd * 8 + (q & 7);   // 0..63
  const int n_tile = q >> 3;              // 0..3
  const int m0 = m_tile * 256, n0 = n_tile * 256;
  const bf16* Wp = W;
  if (wbatch) {
    const int batch = m_tile >> 4;
    Wp = (batch == 3 && Walt) ? Walt : W + (size_t)batch * wbatch;
  }

  const int wave = tid >> 6, lane = tid & 63;
  const int wm = wave >> 2, wn = wave & 3;
  const int quad = lane >> 4, r16 = lane & 15, rxor = r16 & 7;
  const int lrow = lane >> 3, lcol = lane & 7;
  const int gchunk = lcol ^ lrow;
  const int nk = K >> 6;

  // A fp32 geometry: load l covers rows (l>>1)*64 + wave*8 + (lane>>3),
  // cols (l&1)*32 + (lane&7)*4 (4 floats/lane).
  const int arow = wave * 8 + (lane >> 3);
  const float* Ab = A + (size_t)(m0 + arow) * 1024 + (lane & 7) * 4;
  const int wr8  = lane >> 3;               // row & 7
  const int wchb = (lane & 7) >> 1;         // chunk within 32-col half
  const int wlo  = (lane & 1) << 2;         // elem offset 0/4

  auto stageB = [&](int T) {
    bf16* lp = Bs + (T & 1) * 16384;
#pragma unroll
    for (int c = 0; c < 4; ++c) {
      const int rb = c * 64 + wave * 8;
      gload_lds16(Wp + (size_t)(n0 + rb + lrow) * K + T * 64 + gchunk * 8,
                  lp + rb * 64);
    }
  };
  auto loadA = [&](float4* r, int T) {
#pragma unroll
    for (int l = 0; l < 8; ++l)
      r[l] = *(const float4*)(Ab + (size_t)(l >> 1) * 65536 + (l & 1) * 32 + T * 64);
  };
  auto writeA = [&](const float4* r, int T) {
    bf16* lp = As + (T & 1) * 16384;
#pragma unroll
    for (int l = 0; l < 8; ++l) {
      const int row   = (l >> 1) * 64 + arow;
      const int chunk = (l & 1) * 4 + wchb;
      union { uint2 u; unsigned short h[4]; } pk;
      pk.h[0] = f2bf(r[l].x); pk.h[1] = f2bf(r[l].y);
      pk.h[2] = f2bf(r[l].z); pk.h[3] = f2bf(r[l].w);
      *(uint2*)(lp + row * 64 + ((chunk ^ wr8) << 3) + wlo) = pk.u;
    }
  };

  floatx4 acc[8][4];
#pragma unroll
  for (int i = 0; i < 8; ++i)
#pragma unroll
    for (int j = 0; j < 4; ++j) acc[i][j] = (floatx4)0.0f;

  short8 a[4][2], b[2][2];

#define LDA_FRAGS(mh) do {                                                    \
  _Pragma("unroll")                                                           \
  for (int i = 0; i < 4; ++i) {                                               \
    const bf16* base = As + db * 16384 +                                      \
        (wm * 128 + (mh) * 64 + i * 16 + r16) * 64;                           \
    a[i][0] = *(const short8*)(base + ((quad ^ rxor) << 3));                  \
    a[i][1] = *(const short8*)(base + (((4 + quad) ^ rxor) << 3));            \
  } } while (0)

#define LDB_FRAGS(nh) do {                                                    \
  _Pragma("unroll")                                                           \
  for (int j = 0; j < 2; ++j) {                                               \
    const bf16* base = Bs + db * 16384 +                                      \
        (wn * 64 + (nh) * 32 + j * 16 + r16) * 64;                            \
    b[j][0] = *(const short8*)(base + ((quad ^ rxor) << 3));                  \
    b[j][1] = *(const short8*)(base + (((4 + quad) ^ rxor) << 3));            \
  } } while (0)

#define MFMA_QUAD(mh, nh) do {                                                \
  _Pragma("unroll")                                                           \
  for (int i = 0; i < 4; ++i)                                                 \
  _Pragma("unroll")                                                           \
  for (int j = 0; j < 2; ++j) {                                               \
    acc[(mh)*4+i][(nh)*2+j] = __builtin_amdgcn_mfma_f32_16x16x32_bf16(        \
        a[i][0], b[j][0], acc[(mh)*4+i][(nh)*2+j], 0, 0, 0);                  \
    acc[(mh)*4+i][(nh)*2+j] = __builtin_amdgcn_mfma_f32_16x16x32_bf16(        \
        a[i][1], b[j][1], acc[(mh)*4+i][(nh)*2+j], 0, 0, 0);                  \
  } } while (0)

  // Prologue: A(0)->rP, B(0)->Bs[0], A(1)->rA; retire A(0)+B(0); build As[0].
  float4 rP[8], rA[8];
  loadA(rP, 0);
  stageB(0);
  if (nk > 1) { loadA(rA, 1); WAITVM(8); }
  else        { WAITVM(0); }
  writeA(rP, 0);
  asm volatile("s_waitcnt lgkmcnt(0)" ::: "memory");
  __builtin_amdgcn_s_barrier();

  for (int T = 0; T < nk; ++T) {
    const int db = T & 1;
    // ---- P1: quadrant (0,0); stage B(T+1) into the free buffer db^1
    LDA_FRAGS(0); LDB_FRAGS(0);
    if (T + 1 < nk) stageB(T + 1);
    __builtin_amdgcn_s_barrier();
    __builtin_amdgcn_s_setprio(1);
    MFMA_QUAD(0, 0);
    __builtin_amdgcn_s_setprio(0);
    __builtin_amdgcn_s_barrier();
    // ---- P2: quadrant (0,1); A(T+1) regs -> cvt -> As[db^1] (free buffer)
    LDB_FRAGS(1);
    if (T + 1 < nk) { WAITVM(4); writeA(rA, T + 1); }
    __builtin_amdgcn_s_barrier();
    __builtin_amdgcn_s_setprio(1);
    MFMA_QUAD(0, 1);
    __builtin_amdgcn_s_setprio(0);
    __builtin_amdgcn_s_barrier();
    // ---- P3: quadrant (1,1) — last As[db] reads; issue A(T+2) loads
    LDA_FRAGS(1);
    if (T + 2 < nk) loadA(rA, T + 2);
    __builtin_amdgcn_s_barrier();
    __builtin_amdgcn_s_setprio(1);
    MFMA_QUAD(1, 1);
    __builtin_amdgcn_s_setprio(0);
    __builtin_amdgcn_s_barrier();
    // ---- P4: quadrant (1,0); retire B(T+1), keep A(T+2) in flight
    LDB_FRAGS(0);
    __builtin_amdgcn_s_barrier();
    __builtin_amdgcn_s_setprio(1);
    MFMA_QUAD(1, 0);
    __builtin_amdgcn_s_setprio(0);
    if (T + 2 < nk) WAITVM(8);
    else            WAITVM(0);
    __builtin_amdgcn_s_barrier();
  }

#undef LDA_FRAGS
#undef LDB_FRAGS
#undef MFMA_QUAD

  // D mapping (verified m89/m91): row = quad*4 + reg, col = lane&15
#pragma unroll
  for (int jj = 0; jj < 4; ++jj) {
    const int col = n0 + wn * 64 + jj * 16 + r16;
    const float bv = BIAS ? bias[col] : 0.0f;
#pragma unroll
    for (int ii = 0; ii < 8; ++ii) {
      const int rowb = m0 + wm * 128 + ii * 16 + quad * 4;
#pragma unroll
      for (int r = 0; r < 4; ++r) {
        const float v = acc[ii][jj][r] + bv;
        if constexpr (sizeof(TO) == 2)
          C[(size_t)(rowb + r) * ldc + col] = __float2bfloat16(v);
        else
          C[(size_t)(rowb + r) * ldc + col] = v;
      }
    }
  }
}

// ---------------------------------------------------------------------------
// softmax(k over dh=64) + ctx[bh][d][e] += sum_n sk[n,d]*v[n,e]  via MFMA.
// ---------------------------------------------------------------------------
__global__ __launch_bounds__(256)
void softmax_context(const unsigned short* __restrict__ kv, float* __restrict__ ctx) {
  __shared__ unsigned short skT[64 * 130];
  __shared__ unsigned short vT [64 * 130];

  const int tid   = threadIdx.x;
  const int wave  = tid >> 6;
  const int lane  = tid & 63;
  const int bh    = blockIdx.x >> 4;
  const int slice = blockIdx.x & 15;
  const int b     = bh >> 3, h = bh & 7;

  const int quad = lane >> 4;
  const int r16  = lane & 15;
  const int d0   = wave * 16;

  floatx4 acc[4];
#pragma unroll
  for (int j = 0; j < 4; ++j) acc[j] = (floatx4)0.0f;

  const int rgrp = tid >> 3;
  const int c    = tid & 7;

  for (int ch = 0; ch < 2; ++ch) {
#pragma unroll
    for (int p = 0; p < 4; ++p) {
      const int r = p * 32 + rgrp;
      const size_t rowbase =
          (size_t)(b * NSEQ + slice * 256 + ch * 128 + r) * 1024 + h * 64;
      const uint4 k8 = *(const uint4*)(kv + rowbase + c * 8);
      const uint4 v8 = *(const uint4*)(kv + rowbase + 512 + c * 8);
      const unsigned short* kb = (const unsigned short*)&k8;
      const unsigned short* vb = (const unsigned short*)&v8;

      float kf[8];
#pragma unroll
      for (int j = 0; j < 8; ++j) kf[j] = bf2f(kb[j]);
      float mx = kf[0];
#pragma unroll
      for (int j = 1; j < 8; ++j) mx = fmaxf(mx, kf[j]);
      mx = fmaxf(mx, __shfl_xor(mx, 1, 64));
      mx = fmaxf(mx, __shfl_xor(mx, 2, 64));
      mx = fmaxf(mx, __shfl_xor(mx, 4, 64));
      float e[8]; float s = 0.0f;
#pragma unroll
      for (int j = 0; j < 8; ++j) { e[j] = __expf(kf[j] - mx); s += e[j]; }
      s += __shfl_xor(s, 1, 64);
      s += __shfl_xor(s, 2, 64);
      s += __shfl_xor(s, 4, 64);
      const float inv = 1.0f / s;
#pragma unroll
      for (int j = 0; j < 8; ++j) {
        const int d = c * 8 + j;
        skT[d * 130 + r] = f2bf(e[j] * inv);
        vT [d * 130 + r] = vb[j];
      }
    }
    __syncthreads();

#pragma unroll
    for (int kk = 0; kk < 4; ++kk) {
      const int kof = kk * 32 + quad * 8;
      union { short8 v; unsigned u[4]; } afr;
      {
        const unsigned* q = (const unsigned*)(skT + (d0 + r16) * 130 + kof);
        afr.u[0] = q[0]; afr.u[1] = q[1]; afr.u[2] = q[2]; afr.u[3] = q[3];
      }
#pragma unroll
      for (int j = 0; j < 4; ++j) {
        union { short8 v; unsigned u[4]; } bfr;
        const unsigned* q = (const unsigned*)(vT + (j * 16 + r16) * 130 + kof);
        bfr.u[0] = q[0]; bfr.u[1] = q[1]; bfr.u[2] = q[2]; bfr.u[3] = q[3];
        acc[j] = __builtin_amdgcn_mfma_f32_16x16x32_bf16(afr.v, bfr.v, acc[j], 0, 0, 0);
      }
    }
    __syncthreads();
  }

  float* cg = ctx + (size_t)bh * 4096;
#pragma unroll
  for (int j = 0; j < 4; ++j) {
    const int e = j * 16 + r16;
#pragma unroll
    for (int r = 0; r < 4; ++r) {
      const int d = d0 + quad * 4 + r;
      atomicAdd(cg + d * 64 + e, acc[j][r]);
    }
  }
}

// ---------------------------------------------------------------------------
// wqT[c][c'] = bf16(wq[c'][c])   wq fp32 [512][1024]
// ---------------------------------------------------------------------------
__global__ __launch_bounds__(256)
void transpose_wq(const float* __restrict__ wq, bf16* __restrict__ wqT) {
  __shared__ unsigned short t[64 * 68];
  const int tid = threadIdx.x;
  const int c0  = blockIdx.x * 64;
  const int r0  = blockIdx.y * 64;

#pragma unroll
  for (int l = 0; l < 4; ++l) {
    const int s = l * 256 + tid;
    const int row = s >> 4, col4 = s & 15;
    const float4 v = *(const float4*)(wq + (size_t)(r0 + row) * 1024 + c0 + col4 * 4);
    t[row * 68 + col4 * 4 + 0] = f2bf(v.x);
    t[row * 68 + col4 * 4 + 1] = f2bf(v.y);
    t[row * 68 + col4 * 4 + 2] = f2bf(v.z);
    t[row * 68 + col4 * 4 + 3] = f2bf(v.w);
  }
  __syncthreads();
#pragma unroll
  for (int l = 0; l < 2; ++l) {
    const int s = l * 256 + tid;
    const int cc = s >> 3, g = s & 7;
    union { uint4 u; unsigned short h[8]; } o;
#pragma unroll
    for (int u = 0; u < 8; ++u) o.h[u] = t[(g * 8 + u) * 68 + cc];
    *(uint4*)((unsigned short*)wqT + (size_t)(c0 + cc) * 512 + r0 + g * 8) = o.u;
  }
}

// ---------------------------------------------------------------------------
// M2[b*1024+o][h*64+d] = sum_e w_out[o][h*64+e] * ctx[b,h][d][e]; w_out fp32.
// ---------------------------------------------------------------------------
__global__ __launch_bounds__(256)
void build_m2(const float* __restrict__ w_out, const float* __restrict__ ctx,
              bf16* __restrict__ M2) {
  __shared__ unsigned short wo_s[128 * 68];
  __shared__ __align__(16) float ctx_s[4096];

  const int tid = threadIdx.x;
  const int bh  = blockIdx.y;
  const int b   = bh >> 3, h = bh & 7;
  const int o0  = blockIdx.x * 128;

#pragma unroll
  for (int l = 0; l < 8; ++l) {
    const int s = l * 256 + tid;
    const int row = s >> 4, col4 = s & 15;
    const float4 v = *(const float4*)(w_out + (size_t)(o0 + row) * 512 + h * 64 + col4 * 4);
    wo_s[row * 68 + col4 * 4 + 0] = f2bf(v.x);
    wo_s[row * 68 + col4 * 4 + 1] = f2bf(v.y);
    wo_s[row * 68 + col4 * 4 + 2] = f2bf(v.z);
    wo_s[row * 68 + col4 * 4 + 3] = f2bf(v.w);
  }
  const float4* cg = (const float4*)(ctx + (size_t)bh * 4096);
#pragma unroll
  for (int l = 0; l < 4; ++l) ((float4*)ctx_s)[l * 256 + tid] = cg[l * 256 + tid];
  __syncthreads();

  const int o_loc = tid & 127;
  const int dbase = (tid >> 7) * 32;
  float acc[32];
#pragma unroll
  for (int d = 0; d < 32; ++d) acc[d] = 0.0f;

  for (int e = 0; e < 64; ++e) {
    const float wf = bf2f(wo_s[o_loc * 68 + e]);
#pragma unroll
    for (int d = 0; d < 32; ++d)
      acc[d] += wf * ctx_s[(dbase + d) * 64 + e];
  }

  union { uint4 u[4]; unsigned short h[32]; } o;
#pragma unroll
  for (int d = 0; d < 32; ++d) o.h[d] = f2bf(acc[d]);
  unsigned short* dst = (unsigned short*)M2 + (size_t)(b * 1024 + o0 + o_loc) * 512 + h * 64 + dbase;
#pragma unroll
  for (int i = 0; i < 4; ++i) ((uint4*)dst)[i] = o.u[i];
}

// ---------------------------------------------------------------------------
extern "C" void kernel_launch(void* const* d_in, const int* in_sizes, int n_in,
                              void* d_out, int out_size, void* d_ws, size_t ws_size,
                              hipStream_t stream) {
  const float* x     = (const float*)d_in[0];
  const float* w_qkv = (const float*)d_in[1];
  const float* w_out = (const float*)d_in[2];
  const float* b_out = (const float*)d_in[3];
  float* out = (float*)d_out;

  char* wbuf = (char*)d_in[1];
  char* obuf = (char*)d_out;

  bf16*  kv   = (bf16*)obuf;                         // d_out[0,32)
  bf16*  wkvb = (bf16*)(obuf + (size_t)33554432);    // d_out[32,34)
  bf16*  M2   = (bf16*)(obuf + (size_t)35651584);    // d_out[34,38)
  bf16*  wqT  = (bf16*)(obuf + (size_t)39845888);    // d_out[38,39)
  float* ctx  = (float*)(wbuf + 3145728);            // wbuf[3,3.5)
  bf16*  W2   = (bf16*)wbuf;                         // wbuf[0,6): batches 0-2
  bf16*  W2b3 = (bf16*)d_in[2];                      // w_out buf: batch 3

  // 1) wkvb = bf16(w_qkv rows 512..1535) -> d_out[32,34)
  convert_x<<<512, 256, 0, stream>>>(w_qkv + (size_t)INNER * DIM, wkvb);
  // 2) wqT transpose (wq fp32 pristine) -> d_out[38,39)
  transpose_wq<<<dim3(16, 8), 256, 0, stream>>>(w_qkv, wqT);
  // 3) ctx zero (w_kv fp32 dead after 1)
  zero_ctx<<<128, 256, 0, stream>>>(ctx);

  // 4) kv = bf16(x) @ wkvb^T -> d_out[0,32). fp32-A 256x256 tiles.
  gemm256f<bf16, false><<<256, 512, 0, stream>>>(
      x, wkvb, 0, nullptr, nullptr, kv, 1024, DIM);

  // 5) ctx = softmax(k)^T v
  softmax_context<<<512, 256, 0, stream>>>((const unsigned short*)kv, ctx);

  // 6) M2 = w_out folded through ctx -> d_out[34,38)
  build_m2<<<dim3(8, 32), 256, 0, stream>>>(w_out, ctx, M2);

  // 7) W2 = M2 @ wqT^T; rows<3072 -> wbuf[0,6), rows>=3072 -> w_out buf.
  gemm_bt<bf16><<<256, 256, 0, stream>>>(
      M2, 512, wqT, 32, W2, 1024, 512, W2b3, 3072);

  // 8) out = bf16(x) @ W2[b]^T + b_out -> d_out (reads nothing in d_out).
  gemm256f<float, true><<<256, 512, 0, stream>>>(
      x, W2, (size_t)1048576, W2b3, b_out, out, DIM, DIM);
}

// Round 5
// 243.952 us; speedup vs baseline: 1.0523x; 1.0172x over previous
//
#include <hip/hip_runtime.h>
#include <hip/hip_bf16.h>

using bf16 = __hip_bfloat16;
typedef __attribute__((ext_vector_type(8))) short short8;
typedef __attribute__((ext_vector_type(4))) float floatx4;

#define NB 4
#define NSEQ 4096
#define DIM 1024
#define INNER 512
#define TOK (NB * NSEQ)   // 16384

// -------------------------- memory plan (no d_ws) ---------------------------
// xbuf = x input (64 MiB): PRISTINE fp32 the whole run.
// d_out (64 MiB):
//   [0,32)     kv bf16 [16384][1024]   (stage 2 writes, stage 3 reads)
//   [32,34)    wkvb bf16 [1024][1024]  (stage 1; dead after stage 2)
//   [34,38)    M2 bf16 [4096][512]     (stage 4; dead after stage 5)
//   [38,39)    wqT bf16 [1024][512]    (stage 1; dead after stage 5)
//   [40,40.5)  ctx fp32 [32][64][64]   (stage 1 zeroes, 3 accumulates, 4 reads)
//   [0,64)     final output            (stage 6 — reads NOTHING in d_out)
// wbuf = w_qkv input (6 MiB fp32): read only by stage 1, then dead;
//   [0,6)  W2 batches 0..2 bf16        (stage 5 writes, stage 6 reads)
// w_out buf (2 MiB fp32): pristine through stage 4, then
//   W2 batch 3 bf16 [1024][1024]       (stage 5 writes, stage 6 reads)

__device__ inline unsigned short f2bf(float x) {
  union { bf16 h; unsigned short u; } c; c.h = __float2bfloat16(x); return c.u;
}
__device__ inline float bf2f(unsigned short u) {
  return __uint_as_float((unsigned)u << 16);
}

// async global->LDS, 16 B per lane; HW writes lane i at ldsbase + i*16.
__device__ inline void gload_lds16(const bf16* g, bf16* ldsbase) {
  __builtin_amdgcn_global_load_lds(
      (const __attribute__((address_space(1))) void*)g,
      (__attribute__((address_space(3))) void*)ldsbase, 16, 0, 0);
}

#define WAITVM(N) asm volatile("s_waitcnt vmcnt(" #N ")" ::: "memory")

// ---------------------------------------------------------------------------
// Fused prep: blocks [0,512)  convert w_kv fp32 -> wkvb bf16
//             blocks [512,640) transpose wq -> wqT bf16
//             blocks [640,768) zero ctx
// All three regions disjoint (ctx lives in d_out, NOT wbuf, so the zero
// cannot race the w_kv reads).
// ---------------------------------------------------------------------------
__global__ __launch_bounds__(256)
void fused_prep(const float* __restrict__ w_qkv, bf16* __restrict__ wkvb,
                bf16* __restrict__ wqT, float* __restrict__ ctx) {
  const int tid = threadIdx.x;
  const int blk = blockIdx.x;

  if (blk < 512) {
    // convert w_qkv rows 512..1535 (fp32 [1024][1024]) -> bf16
    const size_t i = (size_t)blk * 256 + tid;
    const float* src = w_qkv + (size_t)INNER * DIM + i * 8;
    const float4 a = ((const float4*)src)[0];
    const float4 b = ((const float4*)src)[1];
    union { uint4 u; bf16 h[8]; } p;
    p.h[0] = __float2bfloat16(a.x); p.h[1] = __float2bfloat16(a.y);
    p.h[2] = __float2bfloat16(a.z); p.h[3] = __float2bfloat16(a.w);
    p.h[4] = __float2bfloat16(b.x); p.h[5] = __float2bfloat16(b.y);
    p.h[6] = __float2bfloat16(b.z); p.h[7] = __float2bfloat16(b.w);
    *(uint4*)(wkvb + i * 8) = p.u;
  } else if (blk < 640) {
    // wqT[c][c'] = bf16(wq[c'][c]);  wq fp32 [512][1024]
    __shared__ unsigned short t[64 * 68];
    const int q  = blk - 512;
    const int c0 = (q & 15) * 64;
    const int r0 = (q >> 4) * 64;
#pragma unroll
    for (int l = 0; l < 4; ++l) {
      const int s = l * 256 + tid;
      const int row = s >> 4, col4 = s & 15;
      const float4 v = *(const float4*)(w_qkv + (size_t)(r0 + row) * 1024 + c0 + col4 * 4);
      t[row * 68 + col4 * 4 + 0] = f2bf(v.x);
      t[row * 68 + col4 * 4 + 1] = f2bf(v.y);
      t[row * 68 + col4 * 4 + 2] = f2bf(v.z);
      t[row * 68 + col4 * 4 + 3] = f2bf(v.w);
    }
    __syncthreads();
#pragma unroll
    for (int l = 0; l < 2; ++l) {
      const int s = l * 256 + tid;
      const int cc = s >> 3, g = s & 7;
      union { uint4 u; unsigned short h[8]; } o;
#pragma unroll
      for (int u = 0; u < 8; ++u) o.h[u] = t[(g * 8 + u) * 68 + cc];
      *(uint4*)((unsigned short*)wqT + (size_t)(c0 + cc) * 512 + r0 + g * 8) = o.u;
    }
  } else {
    const int q = blk - 640;
    ((float4*)ctx)[q * 256 + tid] = make_float4(0.f, 0.f, 0.f, 0.f);
  }
}

// ---------------------------------------------------------------------------
// 128x128 GEMM (stage 5). C = A[M,K] @ W[N,K]^T. Rows >= msplit go to Calt.
// ---------------------------------------------------------------------------
template <typename TO>
__global__ __launch_bounds__(256, 4)
void gemm_bt(const bf16* __restrict__ A, int lda,
             const bf16* __restrict__ W, int mTiles,
             TO* __restrict__ C, int ldc, int K,
             TO* __restrict__ Calt, int msplit) {
  __shared__ __align__(16) bf16 As[128 * 64];
  __shared__ __align__(16) bf16 Bs[128 * 64];

  const int tid    = threadIdx.x;
  const int p      = blockIdx.x;
  const int m_tile = p % mTiles;
  const int n_tile = p / mTiles;
  const int m0     = m_tile * 128;
  const int n0     = n_tile * 128;

  const int wave = tid >> 6;
  const int lane = tid & 63;
  const int wr   = (wave >> 1) * 64;
  const int wc   = (wave & 1) * 64;
  const int quad = lane >> 4;
  const int r16  = lane & 15;
  const int rxor = r16 & 7;
  const int lrow = lane >> 3;
  const int lcol = lane & 7;
  const int gchunk = lcol ^ lrow;

  floatx4 acc[4][4];
#pragma unroll
  for (int i = 0; i < 4; ++i)
#pragma unroll
    for (int j = 0; j < 4; ++j) acc[i][j] = (floatx4)0.0f;

  const int ksteps = K >> 6;
  for (int kt = 0; kt < ksteps; ++kt) {
    const int k0 = kt << 6;
#pragma unroll
    for (int t = 0; t < 4; ++t) {
      const int s   = wave * 4 + t;
      const int row = s * 8 + lrow;
      gload_lds16(A + (size_t)(m0 + row) * lda + k0 + gchunk * 8, As + s * 512);
      gload_lds16(W + (size_t)(n0 + row) * K   + k0 + gchunk * 8, Bs + s * 512);
    }
    __syncthreads();
#pragma unroll
    for (int kk = 0; kk < 64; kk += 32) {
      const int cbase = kk >> 3;
      short8 af[4], bfg[4];
#pragma unroll
      for (int i = 0; i < 4; ++i)
        af[i] = *(const short8*)(As + (wr + i * 16 + r16) * 64 + (((quad + cbase) ^ rxor) << 3));
#pragma unroll
      for (int j = 0; j < 4; ++j)
        bfg[j] = *(const short8*)(Bs + (wc + j * 16 + r16) * 64 + (((quad + cbase) ^ rxor) << 3));
#pragma unroll
      for (int i = 0; i < 4; ++i)
#pragma unroll
        for (int j = 0; j < 4; ++j)
          acc[i][j] = __builtin_amdgcn_mfma_f32_16x16x32_bf16(af[i], bfg[j], acc[i][j], 0, 0, 0);
    }
    __syncthreads();
  }

  TO* Cb = C; int radj = 0;
  if (Calt && m0 >= msplit) { Cb = Calt; radj = msplit; }
#pragma unroll
  for (int j = 0; j < 4; ++j) {
    const int col = n0 + wc + j * 16 + r16;
#pragma unroll
    for (int i = 0; i < 4; ++i) {
      const int rowb = m0 + wr + i * 16 + quad * 4 - radj;
#pragma unroll
      for (int r = 0; r < 4; ++r)
        Cb[(size_t)(rowb + r) * ldc + col] = __float2bfloat16(acc[i][j][r]);
    }
  }
}

// ---------------------------------------------------------------------------
// 256x256 4-phase counted-vmcnt GEMM, fp32 A: C = bf16(A)[M,K] @ W[N,K]^T.
// A fp32 reg-staged: each lane owns 8 CONTIGUOUS floats (row wave*8+(lane>>3),
// chunk c8=lane&7) -> one ds_write_b128 per 64-row block at XOR slot c8^wr8.
// Bank check (32-lane half-wave): c8^wr8 spans 0..7 uniformly -> every bank
// exactly 4 accesses = b128 floor (same structure as the 0-conflict frag
// reads). R3's b64 writes hit 16/32 banks per half-wave -> the 1M conflicts.
// B bf16 via global_load_lds. 512 thr = 8 waves (2Mx4N), BK=64, 128 KiB LDS.
// Phases P1(0,b0) P2(0,b1) P3(1,b1) P4(1,b0); b0 frags cached P1->P4.
// VM choreography (per wave, 8 A-loads + 4 B-loads per tile):
//   P1: stageB(T+1)->Bs[db^1];  P2: WAITVM(4) retires A(T+1) (oldest 8),
//   writeA(rA,T+1)->As[db^1] BEFORE frag reads (in-order lgkm ⇒ MFMA's read
//   waits retire the writes; cross-wave visibility by P2's closing barrier);
//   P3: loadA(rA,T+2) (rA dead after P2's write);  P4-end: WAITVM(8) retires
//   B(T+1) exactly, A(T+2) stays in flight. Tail: WAITVM(0) at T>=nk-2.
// XCD swizzle: xcd p&7 owns m_tiles [xcd*8,xcd*8+8) x 4 n_tiles.
// ---------------------------------------------------------------------------
template <typename TO, bool BIAS>
__global__ __launch_bounds__(512, 1)
void gemm256f(const float* __restrict__ A,
              const bf16* __restrict__ W, size_t wbatch,
              const bf16* __restrict__ Walt,
              const float* __restrict__ bias,
              TO* __restrict__ C, int ldc, int K) {
  __shared__ __align__(16) bf16 As[2 * 16384];   // [2][256][64]
  __shared__ __align__(16) bf16 Bs[2 * 16384];

  const int tid  = threadIdx.x;
  const int p    = blockIdx.x;
  const int xcd  = p & 7, q = p >> 3;
  const int m_tile = xcd * 8 + (q & 7);   // 0..63
  const int n_tile = q >> 3;              // 0..3
  const int m0 = m_tile * 256, n0 = n_tile * 256;
  const bf16* Wp = W;
  if (wbatch) {
    const int batch = m_tile >> 4;
    Wp = (batch == 3 && Walt) ? Walt : W + (size_t)batch * wbatch;
  }

  const int wave = tid >> 6, lane = tid & 63;
  const int wm = wave >> 2, wn = wave & 3;
  const int quad = lane >> 4, r16 = lane & 15, rxor = r16 & 7;
  const int lrow = lane >> 3, lcol = lane & 7;
  const int gchunk = lcol ^ lrow;
  const int nk = K >> 6;

  // A fp32 geometry: lane owns rows l*64 + wave*8 + wr8 (l=0..3), cols
  // [c8*8, c8*8+8) within the K-tile. Two dwordx4 loads per row-block.
  const int wr8 = lane >> 3;
  const int c8  = lane & 7;
  const float* Ab = A + (size_t)(m0 + wave * 8 + wr8) * 1024 + c8 * 8;

  auto stageB = [&](int T) {
    bf16* lp = Bs + (T & 1) * 16384;
#pragma unroll
    for (int c = 0; c < 4; ++c) {
      const int rb = c * 64 + wave * 8;
      gload_lds16(Wp + (size_t)(n0 + rb + lrow) * K + T * 64 + gchunk * 8,
                  lp + rb * 64);
    }
  };
  auto loadA = [&](float4* r, int T) {
#pragma unroll
    for (int l = 0; l < 4; ++l) {
      r[2 * l]     = *(const float4*)(Ab + (size_t)l * 65536 + T * 64);
      r[2 * l + 1] = *(const float4*)(Ab + (size_t)l * 65536 + T * 64 + 4);
    }
  };
  auto writeA = [&](const float4* r, int T) {
    bf16* lp = As + (T & 1) * 16384;
#pragma unroll
    for (int l = 0; l < 4; ++l) {
      const int row = l * 64 + wave * 8 + wr8;
      union { uint4 u; unsigned short h[8]; } pk;
      pk.h[0] = f2bf(r[2*l].x);   pk.h[1] = f2bf(r[2*l].y);
      pk.h[2] = f2bf(r[2*l].z);   pk.h[3] = f2bf(r[2*l].w);
      pk.h[4] = f2bf(r[2*l+1].x); pk.h[5] = f2bf(r[2*l+1].y);
      pk.h[6] = f2bf(r[2*l+1].z); pk.h[7] = f2bf(r[2*l+1].w);
      *(uint4*)(lp + row * 64 + ((c8 ^ wr8) << 3)) = pk.u;
    }
  };

  floatx4 acc[8][4];
#pragma unroll
  for (int i = 0; i < 8; ++i)
#pragma unroll
    for (int j = 0; j < 4; ++j) acc[i][j] = (floatx4)0.0f;

  short8 a[4][2], b0[2][2], b1[2][2];

#define LDA_FRAGS(mh) do {                                                    \
  _Pragma("unroll")                                                           \
  for (int i = 0; i < 4; ++i) {                                               \
    const bf16* base = As + db * 16384 +                                      \
        (wm * 128 + (mh) * 64 + i * 16 + r16) * 64;                           \
    a[i][0] = *(const short8*)(base + ((quad ^ rxor) << 3));                  \
    a[i][1] = *(const short8*)(base + (((4 + quad) ^ rxor) << 3));            \
  } } while (0)

#define LDB_FRAGS(bt, nh) do {                                                \
  _Pragma("unroll")                                                           \
  for (int j = 0; j < 2; ++j) {                                               \
    const bf16* base = Bs + db * 16384 +                                      \
        (wn * 64 + (nh) * 32 + j * 16 + r16) * 64;                            \
    bt[j][0] = *(const short8*)(base + ((quad ^ rxor) << 3));                 \
    bt[j][1] = *(const short8*)(base + (((4 + quad) ^ rxor) << 3));           \
  } } while (0)

#define MFMA_QUAD(mh, bt, nh) do {                                            \
  _Pragma("unroll")                                                           \
  for (int i = 0; i < 4; ++i)                                                 \
  _Pragma("unroll")                                                           \
  for (int j = 0; j < 2; ++j) {                                               \
    acc[(mh)*4+i][(nh)*2+j] = __builtin_amdgcn_mfma_f32_16x16x32_bf16(        \
        a[i][0], bt[j][0], acc[(mh)*4+i][(nh)*2+j], 0, 0, 0);                 \
    acc[(mh)*4+i][(nh)*2+j] = __builtin_amdgcn_mfma_f32_16x16x32_bf16(        \
        a[i][1], bt[j][1], acc[(mh)*4+i][(nh)*2+j], 0, 0, 0);                 \
  } } while (0)

  // Prologue: A(0)->rP, B(0)->Bs[0], A(1)->rA; WAITVM(8) retires A(0)+B(0);
  // build As[0]; drain lgkm so all waves see it after the barrier.
  float4 rP[8], rA[8];
  loadA(rP, 0);
  stageB(0);
  if (nk > 1) { loadA(rA, 1); WAITVM(8); }
  else        { WAITVM(0); }
  writeA(rP, 0);
  asm volatile("s_waitcnt lgkmcnt(0)" ::: "memory");
  __builtin_amdgcn_s_barrier();

  for (int T = 0; T < nk; ++T) {
    const int db = T & 1;
    // ---- P1: (mh=0, b0); stage B(T+1) into the free buffer db^1
    LDA_FRAGS(0); LDB_FRAGS(b0, 0);
    if (T + 1 < nk) stageB(T + 1);
    __builtin_amdgcn_s_barrier();
    __builtin_amdgcn_s_setprio(1);
    MFMA_QUAD(0, b0, 0);
    __builtin_amdgcn_s_setprio(0);
    __builtin_amdgcn_s_barrier();
    // ---- P2: (mh=0, b1); retire A(T+1) regs, cvt+write -> As[db^1]
    if (T + 1 < nk) { WAITVM(4); writeA(rA, T + 1); }
    LDB_FRAGS(b1, 1);
    __builtin_amdgcn_s_barrier();
    __builtin_amdgcn_s_setprio(1);
    MFMA_QUAD(0, b1, 1);
    __builtin_amdgcn_s_setprio(0);
    __builtin_amdgcn_s_barrier();
    // ---- P3: (mh=1, b1); rA dead (written at P2) -> issue A(T+2) loads
    LDA_FRAGS(1);
    if (T + 2 < nk) loadA(rA, T + 2);
    __builtin_amdgcn_s_barrier();
    __builtin_amdgcn_s_setprio(1);
    MFMA_QUAD(1, b1, 1);
    __builtin_amdgcn_s_setprio(0);
    __builtin_amdgcn_s_barrier();
    // ---- P4: (mh=1, b0 cached from P1); retire B(T+1), keep A(T+2) flying
    __builtin_amdgcn_s_barrier();
    __builtin_amdgcn_s_setprio(1);
    MFMA_QUAD(1, b0, 0);
    __builtin_amdgcn_s_setprio(0);
    if (T + 2 < nk) WAITVM(8);
    else            WAITVM(0);
    __builtin_amdgcn_s_barrier();
  }

#undef LDA_FRAGS
#undef LDB_FRAGS
#undef MFMA_QUAD

  // D mapping (verified m89/m91): row = quad*4 + reg, col = lane&15
#pragma unroll
  for (int jj = 0; jj < 4; ++jj) {
    const int col = n0 + wn * 64 + jj * 16 + r16;
    const float bv = BIAS ? bias[col] : 0.0f;
#pragma unroll
    for (int ii = 0; ii < 8; ++ii) {
      const int rowb = m0 + wm * 128 + ii * 16 + quad * 4;
#pragma unroll
      for (int r = 0; r < 4; ++r) {
        const float v = acc[ii][jj][r] + bv;
        if constexpr (sizeof(TO) == 2)
          C[(size_t)(rowb + r) * ldc + col] = __float2bfloat16(v);
        else
          C[(size_t)(rowb + r) * ldc + col] = v;
      }
    }
  }
}

// ---------------------------------------------------------------------------
// softmax(k over dh=64) + ctx[bh][d][e] += sum_n sk[n,d]*v[n,e]  via MFMA.
// ---------------------------------------------------------------------------
__global__ __launch_bounds__(256)
void softmax_context(const unsigned short* __restrict__ kv, float* __restrict__ ctx) {
  __shared__ unsigned short skT[64 * 130];
  __shared__ unsigned short vT [64 * 130];

  const int tid   = threadIdx.x;
  const int wave  = tid >> 6;
  const int lane  = tid & 63;
  const int bh    = blockIdx.x >> 4;
  const int slice = blockIdx.x & 15;
  const int b     = bh >> 3, h = bh & 7;

  const int quad = lane >> 4;
  const int r16  = lane & 15;
  const int d0   = wave * 16;

  floatx4 acc[4];
#pragma unroll
  for (int j = 0; j < 4; ++j) acc[j] = (floatx4)0.0f;

  const int rgrp = tid >> 3;
  const int c    = tid & 7;

  for (int ch = 0; ch < 2; ++ch) {
#pragma unroll
    for (int p = 0; p < 4; ++p) {
      const int r = p * 32 + rgrp;
      const size_t rowbase =
          (size_t)(b * NSEQ + slice * 256 + ch * 128 + r) * 1024 + h * 64;
      const uint4 k8 = *(const uint4*)(kv + rowbase + c * 8);
      const uint4 v8 = *(const uint4*)(kv + rowbase + 512 + c * 8);
      const unsigned short* kb = (const unsigned short*)&k8;
      const unsigned short* vb = (const unsigned short*)&v8;

      float kf[8];
#pragma unroll
      for (int j = 0; j < 8; ++j) kf[j] = bf2f(kb[j]);
      float mx = kf[0];
#pragma unroll
      for (int j = 1; j < 8; ++j) mx = fmaxf(mx, kf[j]);
      mx = fmaxf(mx, __shfl_xor(mx, 1, 64));
      mx = fmaxf(mx, __shfl_xor(mx, 2, 64));
      mx = fmaxf(mx, __shfl_xor(mx, 4, 64));
      float e[8]; float s = 0.0f;
#pragma unroll
      for (int j = 0; j < 8; ++j) { e[j] = __expf(kf[j] - mx); s += e[j]; }
      s += __shfl_xor(s, 1, 64);
      s += __shfl_xor(s, 2, 64);
      s += __shfl_xor(s, 4, 64);
      const float inv = 1.0f / s;
#pragma unroll
      for (int j = 0; j < 8; ++j) {
        const int d = c * 8 + j;
        skT[d * 130 + r] = f2bf(e[j] * inv);
        vT [d * 130 + r] = vb[j];
      }
    }
    __syncthreads();

#pragma unroll
    for (int kk = 0; kk < 4; ++kk) {
      const int kof = kk * 32 + quad * 8;
      union { short8 v; unsigned u[4]; } afr;
      {
        const unsigned* q = (const unsigned*)(skT + (d0 + r16) * 130 + kof);
        afr.u[0] = q[0]; afr.u[1] = q[1]; afr.u[2] = q[2]; afr.u[3] = q[3];
      }
#pragma unroll
      for (int j = 0; j < 4; ++j) {
        union { short8 v; unsigned u[4]; } bfr;
        const unsigned* q = (const unsigned*)(vT + (j * 16 + r16) * 130 + kof);
        bfr.u[0] = q[0]; bfr.u[1] = q[1]; bfr.u[2] = q[2]; bfr.u[3] = q[3];
        acc[j] = __builtin_amdgcn_mfma_f32_16x16x32_bf16(afr.v, bfr.v, acc[j], 0, 0, 0);
      }
    }
    __syncthreads();
  }

  float* cg = ctx + (size_t)bh * 4096;
#pragma unroll
  for (int j = 0; j < 4; ++j) {
    const int e = j * 16 + r16;
#pragma unroll
    for (int r = 0; r < 4; ++r) {
      const int d = d0 + quad * 4 + r;
      atomicAdd(cg + d * 64 + e, acc[j][r]);
    }
  }
}

// ---------------------------------------------------------------------------
// M2[b*1024+o][h*64+d] = sum_e w_out[o][h*64+e] * ctx[b,h][d][e]; w_out fp32.
// ---------------------------------------------------------------------------
__global__ __launch_bounds__(256)
void build_m2(const float* __restrict__ w_out, const float* __restrict__ ctx,
              bf16* __restrict__ M2) {
  __shared__ unsigned short wo_s[128 * 68];
  __shared__ __align__(16) float ctx_s[4096];

  const int tid = threadIdx.x;
  const int bh  = blockIdx.y;
  const int b   = bh >> 3, h = bh & 7;
  const int o0  = blockIdx.x * 128;

#pragma unroll
  for (int l = 0; l < 8; ++l) {
    const int s = l * 256 + tid;
    const int row = s >> 4, col4 = s & 15;
    const float4 v = *(const float4*)(w_out + (size_t)(o0 + row) * 512 + h * 64 + col4 * 4);
    wo_s[row * 68 + col4 * 4 + 0] = f2bf(v.x);
    wo_s[row * 68 + col4 * 4 + 1] = f2bf(v.y);
    wo_s[row * 68 + col4 * 4 + 2] = f2bf(v.z);
    wo_s[row * 68 + col4 * 4 + 3] = f2bf(v.w);
  }
  const float4* cg = (const float4*)(ctx + (size_t)bh * 4096);
#pragma unroll
  for (int l = 0; l < 4; ++l) ((float4*)ctx_s)[l * 256 + tid] = cg[l * 256 + tid];
  __syncthreads();

  const int o_loc = tid & 127;
  const int dbase = (tid >> 7) * 32;
  float acc[32];
#pragma unroll
  for (int d = 0; d < 32; ++d) acc[d] = 0.0f;

  for (int e = 0; e < 64; ++e) {
    const float wf = bf2f(wo_s[o_loc * 68 + e]);
#pragma unroll
    for (int d = 0; d < 32; ++d)
      acc[d] += wf * ctx_s[(dbase + d) * 64 + e];
  }

  union { uint4 u[4]; unsigned short h[32]; } o;
#pragma unroll
  for (int d = 0; d < 32; ++d) o.h[d] = f2bf(acc[d]);
  unsigned short* dst = (unsigned short*)M2 + (size_t)(b * 1024 + o0 + o_loc) * 512 + h * 64 + dbase;
#pragma unroll
  for (int i = 0; i < 4; ++i) ((uint4*)dst)[i] = o.u[i];
}

// ---------------------------------------------------------------------------
extern "C" void kernel_launch(void* const* d_in, const int* in_sizes, int n_in,
                              void* d_out, int out_size, void* d_ws, size_t ws_size,
                              hipStream_t stream) {
  const float* x     = (const float*)d_in[0];
  const float* w_qkv = (const float*)d_in[1];
  const float* w_out = (const float*)d_in[2];
  const float* b_out = (const float*)d_in[3];
  float* out = (float*)d_out;

  char* wbuf = (char*)d_in[1];
  char* obuf = (char*)d_out;

  bf16*  kv   = (bf16*)obuf;                         // d_out[0,32)
  bf16*  wkvb = (bf16*)(obuf + (size_t)33554432);    // d_out[32,34)
  bf16*  M2   = (bf16*)(obuf + (size_t)35651584);    // d_out[34,38)
  bf16*  wqT  = (bf16*)(obuf + (size_t)39845888);    // d_out[38,39)
  float* ctx  = (float*)(obuf + (size_t)41943040);   // d_out[40,40.5)
  bf16*  W2   = (bf16*)wbuf;                         // wbuf[0,6): batches 0-2
  bf16*  W2b3 = (bf16*)d_in[2];                      // w_out buf: batch 3

  // 1) fused prep: wkvb convert + wqT transpose + ctx zero (disjoint regions)
  fused_prep<<<768, 256, 0, stream>>>(w_qkv, wkvb, wqT, ctx);

  // 2) kv = bf16(x) @ wkvb^T -> d_out[0,32). fp32-A 256x256 tiles.
  gemm256f<bf16, false><<<256, 512, 0, stream>>>(
      x, wkvb, 0, nullptr, nullptr, kv, 1024, DIM);

  // 3) ctx = softmax(k)^T v
  softmax_context<<<512, 256, 0, stream>>>((const unsigned short*)kv, ctx);

  // 4) M2 = w_out folded through ctx -> d_out[34,38)
  build_m2<<<dim3(8, 32), 256, 0, stream>>>(w_out, ctx, M2);

  // 5) W2 = M2 @ wqT^T; rows<3072 -> wbuf[0,6), rows>=3072 -> w_out buf.
  gemm_bt<bf16><<<256, 256, 0, stream>>>(
      M2, 512, wqT, 32, W2, 1024, 512, W2b3, 3072);

  // 6) out = bf16(x) @ W2[b]^T + b_out -> d_out (reads nothing in d_out).
  gemm256f<float, true><<<256, 512, 0, stream>>>(
      x, W2, (size_t)1048576, W2b3, b_out, out, DIM, DIM);
}

// Round 6
// 242.527 us; speedup vs baseline: 1.0585x; 1.0059x over previous
//
#include <hip/hip_runtime.h>
#include <hip/hip_bf16.h>

using bf16 = __hip_bfloat16;
typedef __attribute__((ext_vector_type(8))) short short8;
typedef __attribute__((ext_vector_type(4))) float floatx4;

#define NB 4
#define NSEQ 4096
#define DIM 1024
#define INNER 512
#define TOK (NB * NSEQ)   // 16384

// -------------------------- memory plan (no d_ws) ---------------------------
// xbuf = x input (64 MiB): PRISTINE fp32 the whole run.
// d_out (64 MiB):
//   [0,32)     kv bf16 [16384][1024]   (stage 2 writes, stage 3 reads)
//   [32,34)    wkvb bf16 [1024][1024]  (stage 1; dead after stage 2)
//   [34,38)    M2 bf16 [4096][512]     (stage 4; dead after stage 5)
//   [38,39)    wqT bf16 [1024][512]    (stage 1; dead after stage 5)
//   [40,40.5)  ctx fp32 [32][64][64]   (stage 1 zeroes, 3 accumulates, 4 reads)
//   [0,64)     final output            (stage 6 — reads NOTHING in d_out)
// wbuf = w_qkv input (6 MiB fp32): read only by stage 1, then dead;
//   [0,6)  W2 batches 0..2 bf16        (stage 5 writes, stage 6 reads)
// w_out buf (2 MiB fp32): pristine through stage 4, then
//   W2 batch 3 bf16 [1024][1024]       (stage 5 writes, stage 6 reads)

__device__ inline unsigned short f2bf(float x) {
  union { bf16 h; unsigned short u; } c; c.h = __float2bfloat16(x); return c.u;
}
__device__ inline float bf2f(unsigned short u) {
  return __uint_as_float((unsigned)u << 16);
}

// async global->LDS, 16 B per lane; HW writes lane i at ldsbase + i*16.
__device__ inline void gload_lds16(const bf16* g, bf16* ldsbase) {
  __builtin_amdgcn_global_load_lds(
      (const __attribute__((address_space(1))) void*)g,
      (__attribute__((address_space(3))) void*)ldsbase, 16, 0, 0);
}

#define WAITVM(N) asm volatile("s_waitcnt vmcnt(" #N ")" ::: "memory")

// ---------------------------------------------------------------------------
// Fused prep: blocks [0,512)  convert w_kv fp32 -> wkvb bf16
//             blocks [512,640) transpose wq -> wqT bf16
//             blocks [640,768) zero ctx
// ---------------------------------------------------------------------------
__global__ __launch_bounds__(256)
void fused_prep(const float* __restrict__ w_qkv, bf16* __restrict__ wkvb,
                bf16* __restrict__ wqT, float* __restrict__ ctx) {
  const int tid = threadIdx.x;
  const int blk = blockIdx.x;

  if (blk < 512) {
    // convert w_qkv rows 512..1535 (fp32 [1024][1024]) -> bf16
    const size_t i = (size_t)blk * 256 + tid;
    const float* src = w_qkv + (size_t)INNER * DIM + i * 8;
    const float4 a = ((const float4*)src)[0];
    const float4 b = ((const float4*)src)[1];
    union { uint4 u; bf16 h[8]; } p;
    p.h[0] = __float2bfloat16(a.x); p.h[1] = __float2bfloat16(a.y);
    p.h[2] = __float2bfloat16(a.z); p.h[3] = __float2bfloat16(a.w);
    p.h[4] = __float2bfloat16(b.x); p.h[5] = __float2bfloat16(b.y);
    p.h[6] = __float2bfloat16(b.z); p.h[7] = __float2bfloat16(b.w);
    *(uint4*)(wkvb + i * 8) = p.u;
  } else if (blk < 640) {
    // wqT[c][c'] = bf16(wq[c'][c]);  wq fp32 [512][1024]
    __shared__ unsigned short t[64 * 68];
    const int q  = blk - 512;
    const int c0 = (q & 15) * 64;
    const int r0 = (q >> 4) * 64;
#pragma unroll
    for (int l = 0; l < 4; ++l) {
      const int s = l * 256 + tid;
      const int row = s >> 4, col4 = s & 15;
      const float4 v = *(const float4*)(w_qkv + (size_t)(r0 + row) * 1024 + c0 + col4 * 4);
      t[row * 68 + col4 * 4 + 0] = f2bf(v.x);
      t[row * 68 + col4 * 4 + 1] = f2bf(v.y);
      t[row * 68 + col4 * 4 + 2] = f2bf(v.z);
      t[row * 68 + col4 * 4 + 3] = f2bf(v.w);
    }
    __syncthreads();
#pragma unroll
    for (int l = 0; l < 2; ++l) {
      const int s = l * 256 + tid;
      const int cc = s >> 3, g = s & 7;
      union { uint4 u; unsigned short h[8]; } o;
#pragma unroll
      for (int u = 0; u < 8; ++u) o.h[u] = t[(g * 8 + u) * 68 + cc];
      *(uint4*)((unsigned short*)wqT + (size_t)(c0 + cc) * 512 + r0 + g * 8) = o.u;
    }
  } else {
    const int q = blk - 640;
    ((float4*)ctx)[q * 256 + tid] = make_float4(0.f, 0.f, 0.f, 0.f);
  }
}

// ---------------------------------------------------------------------------
// 128x128 GEMM (stage 5). C = A[M,K] @ W[N,K]^T. Rows >= msplit go to Calt.
// ---------------------------------------------------------------------------
template <typename TO>
__global__ __launch_bounds__(256, 4)
void gemm_bt(const bf16* __restrict__ A, int lda,
             const bf16* __restrict__ W, int mTiles,
             TO* __restrict__ C, int ldc, int K,
             TO* __restrict__ Calt, int msplit) {
  __shared__ __align__(16) bf16 As[128 * 64];
  __shared__ __align__(16) bf16 Bs[128 * 64];

  const int tid    = threadIdx.x;
  const int p      = blockIdx.x;
  const int m_tile = p % mTiles;
  const int n_tile = p / mTiles;
  const int m0     = m_tile * 128;
  const int n0     = n_tile * 128;

  const int wave = tid >> 6;
  const int lane = tid & 63;
  const int wr   = (wave >> 1) * 64;
  const int wc   = (wave & 1) * 64;
  const int quad = lane >> 4;
  const int r16  = lane & 15;
  const int rxor = r16 & 7;
  const int lrow = lane >> 3;
  const int lcol = lane & 7;
  const int gchunk = lcol ^ lrow;

  floatx4 acc[4][4];
#pragma unroll
  for (int i = 0; i < 4; ++i)
#pragma unroll
    for (int j = 0; j < 4; ++j) acc[i][j] = (floatx4)0.0f;

  const int ksteps = K >> 6;
  for (int kt = 0; kt < ksteps; ++kt) {
    const int k0 = kt << 6;
#pragma unroll
    for (int t = 0; t < 4; ++t) {
      const int s   = wave * 4 + t;
      const int row = s * 8 + lrow;
      gload_lds16(A + (size_t)(m0 + row) * lda + k0 + gchunk * 8, As + s * 512);
      gload_lds16(W + (size_t)(n0 + row) * K   + k0 + gchunk * 8, Bs + s * 512);
    }
    __syncthreads();
#pragma unroll
    for (int kk = 0; kk < 64; kk += 32) {
      const int cbase = kk >> 3;
      short8 af[4], bfg[4];
#pragma unroll
      for (int i = 0; i < 4; ++i)
        af[i] = *(const short8*)(As + (wr + i * 16 + r16) * 64 + (((quad + cbase) ^ rxor) << 3));
#pragma unroll
      for (int j = 0; j < 4; ++j)
        bfg[j] = *(const short8*)(Bs + (wc + j * 16 + r16) * 64 + (((quad + cbase) ^ rxor) << 3));
#pragma unroll
      for (int i = 0; i < 4; ++i)
#pragma unroll
        for (int j = 0; j < 4; ++j)
          acc[i][j] = __builtin_amdgcn_mfma_f32_16x16x32_bf16(af[i], bfg[j], acc[i][j], 0, 0, 0);
    }
    __syncthreads();
  }

  TO* Cb = C; int radj = 0;
  if (Calt && m0 >= msplit) { Cb = Calt; radj = msplit; }
#pragma unroll
  for (int j = 0; j < 4; ++j) {
    const int col = n0 + wc + j * 16 + r16;
#pragma unroll
    for (int i = 0; i < 4; ++i) {
      const int rowb = m0 + wr + i * 16 + quad * 4 - radj;
#pragma unroll
      for (int r = 0; r < 4; ++r)
        Cb[(size_t)(rowb + r) * ldc + col] = __float2bfloat16(acc[i][j][r]);
    }
  }
}

// ---------------------------------------------------------------------------
// 256x256 3-phase counted-vmcnt GEMM, fp32 A: C = bf16(A)[M,K] @ W[N,K]^T.
// R5 post-mortem: bank conflicts = 0 but dur stuck at 62.5us -> the stall was
// P2's {WAITVM -> cvt -> ds_write -> ds_read -> MFMA} chain (in-order lgkm
// queues writes ahead of the frag reads the MFMA needs; 1 block/CU means the
// closing barrier propagates the stall to all waves). Restructure:
//  P1: {LDA0 + LDB b0 reads; stageB(T+1) | 16 MFMA(0,b0)}
//  P2: {LDB b1 reads | 16 MFMA(0,b1); THEN WAITVM(4)+cvt+writeA(T+1)}
//  P3 (merged old P3+P4): {LDA1 reads; loadA(T+2) issue | 32 MFMA(1,b1)+(1,b0
//      cached from P1); WAITVM(8)}
// 6 barriers/tile (was 8). A-staging is never upstream of same-phase MFMA.
// Write safety: writeA targets As[db^1], last read iter T-1 (>=2 barriers
// back); writes retire before my P3 MFMA's lgkm wait (in-order), consumers
// read at T+1 P1 after 3 more barriers. vm counts: P2-end WAITVM(4) retires
// exactly A(T+1) (oldest 8 of {A(T+1)8, B(T+1)4}); P3-end WAITVM(8) retires
// exactly B(T+1), leaving A(T+2) in flight. Tail T+2>=nk: WAITVM(0).
// XCD swizzle: xcd p&7 owns m_tiles [xcd*8,xcd*8+8) x 4 n_tiles.
// ---------------------------------------------------------------------------
template <typename TO, bool BIAS>
__global__ __launch_bounds__(512, 1)
void gemm256f(const float* __restrict__ A,
              const bf16* __restrict__ W, size_t wbatch,
              const bf16* __restrict__ Walt,
              const float* __restrict__ bias,
              TO* __restrict__ C, int ldc, int K) {
  __shared__ __align__(16) bf16 As[2 * 16384];   // [2][256][64]
  __shared__ __align__(16) bf16 Bs[2 * 16384];

  const int tid  = threadIdx.x;
  const int p    = blockIdx.x;
  const int xcd  = p & 7, q = p >> 3;
  const int m_tile = xcd * 8 + (q & 7);   // 0..63
  const int n_tile = q >> 3;              // 0..3
  const int m0 = m_tile * 256, n0 = n_tile * 256;
  const bf16* Wp = W;
  if (wbatch) {
    const int batch = m_tile >> 4;
    Wp = (batch == 3 && Walt) ? Walt : W + (size_t)batch * wbatch;
  }

  const int wave = tid >> 6, lane = tid & 63;
  const int wm = wave >> 2, wn = wave & 3;
  const int quad = lane >> 4, r16 = lane & 15, rxor = r16 & 7;
  const int lrow = lane >> 3, lcol = lane & 7;
  const int gchunk = lcol ^ lrow;
  const int nk = K >> 6;

  // A fp32 geometry: lane owns rows l*64 + wave*8 + wr8 (l=0..3), cols
  // [c8*8, c8*8+8) within the K-tile. Two dwordx4 loads per row-block.
  const int wr8 = lane >> 3;
  const int c8  = lane & 7;
  const float* Ab = A + (size_t)(m0 + wave * 8 + wr8) * 1024 + c8 * 8;

  auto stageB = [&](int T) {
    bf16* lp = Bs + (T & 1) * 16384;
#pragma unroll
    for (int c = 0; c < 4; ++c) {
      const int rb = c * 64 + wave * 8;
      gload_lds16(Wp + (size_t)(n0 + rb + lrow) * K + T * 64 + gchunk * 8,
                  lp + rb * 64);
    }
  };
  auto loadA = [&](float4* r, int T) {
#pragma unroll
    for (int l = 0; l < 4; ++l) {
      r[2 * l]     = *(const float4*)(Ab + (size_t)l * 65536 + T * 64);
      r[2 * l + 1] = *(const float4*)(Ab + (size_t)l * 65536 + T * 64 + 4);
    }
  };
  auto writeA = [&](const float4* r, int T) {
    bf16* lp = As + (T & 1) * 16384;
#pragma unroll
    for (int l = 0; l < 4; ++l) {
      const int row = l * 64 + wave * 8 + wr8;
      union { uint4 u; unsigned short h[8]; } pk;
      pk.h[0] = f2bf(r[2*l].x);   pk.h[1] = f2bf(r[2*l].y);
      pk.h[2] = f2bf(r[2*l].z);   pk.h[3] = f2bf(r[2*l].w);
      pk.h[4] = f2bf(r[2*l+1].x); pk.h[5] = f2bf(r[2*l+1].y);
      pk.h[6] = f2bf(r[2*l+1].z); pk.h[7] = f2bf(r[2*l+1].w);
      *(uint4*)(lp + row * 64 + ((c8 ^ wr8) << 3)) = pk.u;
    }
  };

  floatx4 acc[8][4];
#pragma unroll
  for (int i = 0; i < 8; ++i)
#pragma unroll
    for (int j = 0; j < 4; ++j) acc[i][j] = (floatx4)0.0f;

  short8 a[4][2], b0[2][2], b1[2][2];

#define LDA_FRAGS(mh) do {                                                    \
  _Pragma("unroll")                                                           \
  for (int i = 0; i < 4; ++i) {                                               \
    const bf16* base = As + db * 16384 +                                      \
        (wm * 128 + (mh) * 64 + i * 16 + r16) * 64;                           \
    a[i][0] = *(const short8*)(base + ((quad ^ rxor) << 3));                  \
    a[i][1] = *(const short8*)(base + (((4 + quad) ^ rxor) << 3));            \
  } } while (0)

#define LDB_FRAGS(bt, nh) do {                                                \
  _Pragma("unroll")                                                           \
  for (int j = 0; j < 2; ++j) {                                               \
    const bf16* base = Bs + db * 16384 +                                      \
        (wn * 64 + (nh) * 32 + j * 16 + r16) * 64;                            \
    bt[j][0] = *(const short8*)(base + ((quad ^ rxor) << 3));                 \
    bt[j][1] = *(const short8*)(base + (((4 + quad) ^ rxor) << 3));           \
  } } while (0)

#define MFMA_QUAD(mh, bt, nh) do {                                            \
  _Pragma("unroll")                                                           \
  for (int i = 0; i < 4; ++i)                                                 \
  _Pragma("unroll")                                                           \
  for (int j = 0; j < 2; ++j) {                                               \
    acc[(mh)*4+i][(nh)*2+j] = __builtin_amdgcn_mfma_f32_16x16x32_bf16(        \
        a[i][0], bt[j][0], acc[(mh)*4+i][(nh)*2+j], 0, 0, 0);                 \
    acc[(mh)*4+i][(nh)*2+j] = __builtin_amdgcn_mfma_f32_16x16x32_bf16(        \
        a[i][1], bt[j][1], acc[(mh)*4+i][(nh)*2+j], 0, 0, 0);                 \
  } } while (0)

  // Prologue: A(0)->rP, B(0)->Bs[0], A(1)->rA; WAITVM(8) retires A(0)+B(0);
  // build As[0]; drain lgkm so all waves see it after the barrier.
  float4 rP[8], rA[8];
  loadA(rP, 0);
  stageB(0);
  if (nk > 1) { loadA(rA, 1); WAITVM(8); }
  else        { WAITVM(0); }
  writeA(rP, 0);
  asm volatile("s_waitcnt lgkmcnt(0)" ::: "memory");
  __builtin_amdgcn_s_barrier();

  for (int T = 0; T < nk; ++T) {
    const int db = T & 1;
    // ---- P1: (mh=0, b0); stage B(T+1) into the free buffer db^1
    LDA_FRAGS(0); LDB_FRAGS(b0, 0);
    if (T + 1 < nk) stageB(T + 1);
    __builtin_amdgcn_s_barrier();
    __builtin_amdgcn_s_setprio(1);
    MFMA_QUAD(0, b0, 0);
    __builtin_amdgcn_s_setprio(0);
    __builtin_amdgcn_s_barrier();
    // ---- P2: (mh=0, b1); MFMA first, THEN retire A(T+1) + cvt + ds_write
    LDB_FRAGS(b1, 1);
    __builtin_amdgcn_s_barrier();
    __builtin_amdgcn_s_setprio(1);
    MFMA_QUAD(0, b1, 1);
    __builtin_amdgcn_s_setprio(0);
    if (T + 1 < nk) { WAITVM(4); writeA(rA, T + 1); }
    __builtin_amdgcn_s_barrier();
    // ---- P3 (merged): (mh=1, b1) + (mh=1, b0 cached); issue A(T+2) loads
    LDA_FRAGS(1);
    if (T + 2 < nk) loadA(rA, T + 2);
    __builtin_amdgcn_s_barrier();
    __builtin_amdgcn_s_setprio(1);
    MFMA_QUAD(1, b1, 1);
    MFMA_QUAD(1, b0, 0);
    __builtin_amdgcn_s_setprio(0);
    if (T + 2 < nk) WAITVM(8);   // retire B(T+1); A(T+2) stays in flight
    else            WAITVM(0);   // tail drain
    __builtin_amdgcn_s_barrier();
  }

#undef LDA_FRAGS
#undef LDB_FRAGS
#undef MFMA_QUAD

  // D mapping (verified m89/m91): row = quad*4 + reg, col = lane&15
#pragma unroll
  for (int jj = 0; jj < 4; ++jj) {
    const int col = n0 + wn * 64 + jj * 16 + r16;
    const float bv = BIAS ? bias[col] : 0.0f;
#pragma unroll
    for (int ii = 0; ii < 8; ++ii) {
      const int rowb = m0 + wm * 128 + ii * 16 + quad * 4;
#pragma unroll
      for (int r = 0; r < 4; ++r) {
        const float v = acc[ii][jj][r] + bv;
        if constexpr (sizeof(TO) == 2)
          C[(size_t)(rowb + r) * ldc + col] = __float2bfloat16(v);
        else
          C[(size_t)(rowb + r) * ldc + col] = v;
      }
    }
  }
}

// ---------------------------------------------------------------------------
// softmax(k over dh=64) + ctx[bh][d][e] += sum_n sk[n,d]*v[n,e]  via MFMA.
// ---------------------------------------------------------------------------
__global__ __launch_bounds__(256)
void softmax_context(const unsigned short* __restrict__ kv, float* __restrict__ ctx) {
  __shared__ unsigned short skT[64 * 130];
  __shared__ unsigned short vT [64 * 130];

  const int tid   = threadIdx.x;
  const int wave  = tid >> 6;
  const int lane  = tid & 63;
  const int bh    = blockIdx.x >> 4;
  const int slice = blockIdx.x & 15;
  const int b     = bh >> 3, h = bh & 7;

  const int quad = lane >> 4;
  const int r16  = lane & 15;
  const int d0   = wave * 16;

  floatx4 acc[4];
#pragma unroll
  for (int j = 0; j < 4; ++j) acc[j] = (floatx4)0.0f;

  const int rgrp = tid >> 3;
  const int c    = tid & 7;

  for (int ch = 0; ch < 2; ++ch) {
#pragma unroll
    for (int p = 0; p < 4; ++p) {
      const int r = p * 32 + rgrp;
      const size_t rowbase =
          (size_t)(b * NSEQ + slice * 256 + ch * 128 + r) * 1024 + h * 64;
      const uint4 k8 = *(const uint4*)(kv + rowbase + c * 8);
      const uint4 v8 = *(const uint4*)(kv + rowbase + 512 + c * 8);
      const unsigned short* kb = (const unsigned short*)&k8;
      const unsigned short* vb = (const unsigned short*)&v8;

      float kf[8];
#pragma unroll
      for (int j = 0; j < 8; ++j) kf[j] = bf2f(kb[j]);
      float mx = kf[0];
#pragma unroll
      for (int j = 1; j < 8; ++j) mx = fmaxf(mx, kf[j]);
      mx = fmaxf(mx, __shfl_xor(mx, 1, 64));
      mx = fmaxf(mx, __shfl_xor(mx, 2, 64));
      mx = fmaxf(mx, __shfl_xor(mx, 4, 64));
      float e[8]; float s = 0.0f;
#pragma unroll
      for (int j = 0; j < 8; ++j) { e[j] = __expf(kf[j] - mx); s += e[j]; }
      s += __shfl_xor(s, 1, 64);
      s += __shfl_xor(s, 2, 64);
      s += __shfl_xor(s, 4, 64);
      const float inv = 1.0f / s;
#pragma unroll
      for (int j = 0; j < 8; ++j) {
        const int d = c * 8 + j;
        skT[d * 130 + r] = f2bf(e[j] * inv);
        vT [d * 130 + r] = vb[j];
      }
    }
    __syncthreads();

#pragma unroll
    for (int kk = 0; kk < 4; ++kk) {
      const int kof = kk * 32 + quad * 8;
      union { short8 v; unsigned u[4]; } afr;
      {
        const unsigned* q = (const unsigned*)(skT + (d0 + r16) * 130 + kof);
        afr.u[0] = q[0]; afr.u[1] = q[1]; afr.u[2] = q[2]; afr.u[3] = q[3];
      }
#pragma unroll
      for (int j = 0; j < 4; ++j) {
        union { short8 v; unsigned u[4]; } bfr;
        const unsigned* q = (const unsigned*)(vT + (j * 16 + r16) * 130 + kof);
        bfr.u[0] = q[0]; bfr.u[1] = q[1]; bfr.u[2] = q[2]; bfr.u[3] = q[3];
        acc[j] = __builtin_amdgcn_mfma_f32_16x16x32_bf16(afr.v, bfr.v, acc[j], 0, 0, 0);
      }
    }
    __syncthreads();
  }

  float* cg = ctx + (size_t)bh * 4096;
#pragma unroll
  for (int j = 0; j < 4; ++j) {
    const int e = j * 16 + r16;
#pragma unroll
    for (int r = 0; r < 4; ++r) {
      const int d = d0 + quad * 4 + r;
      atomicAdd(cg + d * 64 + e, acc[j][r]);
    }
  }
}

// ---------------------------------------------------------------------------
// M2[b*1024+o][h*64+d] = sum_e w_out[o][h*64+e] * ctx[b,h][d][e]; w_out fp32.
// ---------------------------------------------------------------------------
__global__ __launch_bounds__(256)
void build_m2(const float* __restrict__ w_out, const float* __restrict__ ctx,
              bf16* __restrict__ M2) {
  __shared__ unsigned short wo_s[128 * 68];
  __shared__ __align__(16) float ctx_s[4096];

  const int tid = threadIdx.x;
  const int bh  = blockIdx.y;
  const int b   = bh >> 3, h = bh & 7;
  const int o0  = blockIdx.x * 128;

#pragma unroll
  for (int l = 0; l < 8; ++l) {
    const int s = l * 256 + tid;
    const int row = s >> 4, col4 = s & 15;
    const float4 v = *(const float4*)(w_out + (size_t)(o0 + row) * 512 + h * 64 + col4 * 4);
    wo_s[row * 68 + col4 * 4 + 0] = f2bf(v.x);
    wo_s[row * 68 + col4 * 4 + 1] = f2bf(v.y);
    wo_s[row * 68 + col4 * 4 + 2] = f2bf(v.z);
    wo_s[row * 68 + col4 * 4 + 3] = f2bf(v.w);
  }
  const float4* cg = (const float4*)(ctx + (size_t)bh * 4096);
#pragma unroll
  for (int l = 0; l < 4; ++l) ((float4*)ctx_s)[l * 256 + tid] = cg[l * 256 + tid];
  __syncthreads();

  const int o_loc = tid & 127;
  const int dbase = (tid >> 7) * 32;
  float acc[32];
#pragma unroll
  for (int d = 0; d < 32; ++d) acc[d] = 0.0f;

  for (int e = 0; e < 64; ++e) {
    const float wf = bf2f(wo_s[o_loc * 68 + e]);
#pragma unroll
    for (int d = 0; d < 32; ++d)
      acc[d] += wf * ctx_s[(dbase + d) * 64 + e];
  }

  union { uint4 u[4]; unsigned short h[32]; } o;
#pragma unroll
  for (int d = 0; d < 32; ++d) o.h[d] = f2bf(acc[d]);
  unsigned short* dst = (unsigned short*)M2 + (size_t)(b * 1024 + o0 + o_loc) * 512 + h * 64 + dbase;
#pragma unroll
  for (int i = 0; i < 4; ++i) ((uint4*)dst)[i] = o.u[i];
}

// ---------------------------------------------------------------------------
extern "C" void kernel_launch(void* const* d_in, const int* in_sizes, int n_in,
                              void* d_out, int out_size, void* d_ws, size_t ws_size,
                              hipStream_t stream) {
  const float* x     = (const float*)d_in[0];
  const float* w_qkv = (const float*)d_in[1];
  const float* w_out = (const float*)d_in[2];
  const float* b_out = (const float*)d_in[3];
  float* out = (float*)d_out;

  char* wbuf = (char*)d_in[1];
  char* obuf = (char*)d_out;

  bf16*  kv   = (bf16*)obuf;                         // d_out[0,32)
  bf16*  wkvb = (bf16*)(obuf + (size_t)33554432);    // d_out[32,34)
  bf16*  M2   = (bf16*)(obuf + (size_t)35651584);    // d_out[34,38)
  bf16*  wqT  = (bf16*)(obuf + (size_t)39845888);    // d_out[38,39)
  float* ctx  = (float*)(obuf + (size_t)41943040);   // d_out[40,40.5)
  bf16*  W2   = (bf16*)wbuf;                         // wbuf[0,6): batches 0-2
  bf16*  W2b3 = (bf16*)d_in[2];                      // w_out buf: batch 3

  // 1) fused prep: wkvb convert + wqT transpose + ctx zero (disjoint regions)
  fused_prep<<<768, 256, 0, stream>>>(w_qkv, wkvb, wqT, ctx);

  // 2) kv = bf16(x) @ wkvb^T -> d_out[0,32). fp32-A 256x256 tiles.
  gemm256f<bf16, false><<<256, 512, 0, stream>>>(
      x, wkvb, 0, nullptr, nullptr, kv, 1024, DIM);

  // 3) ctx = softmax(k)^T v
  softmax_context<<<512, 256, 0, stream>>>((const unsigned short*)kv, ctx);

  // 4) M2 = w_out folded through ctx -> d_out[34,38)
  build_m2<<<dim3(8, 32), 256, 0, stream>>>(w_out, ctx, M2);

  // 5) W2 = M2 @ wqT^T; rows<3072 -> wbuf[0,6), rows>=3072 -> w_out buf.
  gemm_bt<bf16><<<256, 256, 0, stream>>>(
      M2, 512, wqT, 32, W2, 1024, 512, W2b3, 3072);

  // 6) out = bf16(x) @ W2[b]^T + b_out -> d_out (reads nothing in d_out).
  gemm256f<float, true><<<256, 512, 0, stream>>>(
      x, W2, (size_t)1048576, W2b3, b_out, out, DIM, DIM);
}